// Round 11
// baseline (689.094 us; speedup 1.0000x reference)
//
#include <hip/hip_runtime.h>
#include <hip/hip_bf16.h>

#define B_ 32
#define N_ 512
#define NB_ 10
#define E_ 1024
#define H_ 256
#define A_ 82
#define K_ 4
#define D_ 3
#define M_ (B_*N_)   // 16384 rows

typedef unsigned short u16;
typedef __attribute__((ext_vector_type(8))) short bf16x8;
typedef __attribute__((ext_vector_type(4))) float f32x4;

__device__ __forceinline__ float b2f(u16 u){
    unsigned int x = ((unsigned int)u) << 16;
    return __builtin_bit_cast(float, x);
}
__device__ __forceinline__ u16 f2b(float f){
    unsigned int x = __builtin_bit_cast(unsigned int, f);
    unsigned int lsb = (x >> 16) & 1u;
    x += 0x7fffu + lsb;
    return (u16)(x >> 16);
}
__device__ __forceinline__ float sigmoidf_(float x){ return 1.f/(1.f+expf(-x)); }

// ---- conversion table: 31 float tensors (atom excluded; ints excluded) ----
static constexpr int CVT_N[31] = {
    B_*E_*6, B_*N_*NB_, B_*N_,
    A_*H_, H_,
    D_*K_*H_*H_, D_*K_*H_, D_*K_*H_*H_, D_*K_*H_,
    D_*K_*H_*H_, D_*K_*H_, D_*K_*H_, D_*K_,
    D_*K_*H_*H_, D_*H_, D_*H_*H_, D_*H_,
    D_*H_*H_, D_*H_, D_*H_*H_, D_*H_,
    D_*H_*H_, D_*H_, D_*H_*H_, D_*H_,
    D_*H_*H_, D_*H_, D_*(H_+6)*H_, D_*H_,
    D_*2*H_*H_, D_*H_
};
struct Offs { long v[32]; };
static constexpr Offs mk_offs(){
    Offs o{}; o.v[0]=0;
    for(int i=0;i<31;i++) o.v[i+1]=o.v[i]+CVT_N[i];
    return o;
}
static constexpr Offs CVT_OFF = mk_offs();

struct Ptrs { const void* p[31]; };

// ---------------- dtype detection: bf16 vs f32 ----------------
__global__ void k_detect(const unsigned short* __restrict__ wv_raw, int* __restrict__ flag){
    float v = b2f(wv_raw[threadIdx.x]);
    bool plaus = (v==v) && (fabsf(v) < 100.0f);
    unsigned long long m = __ballot(plaus);
    if (threadIdx.x==0) *flag = (m == ~0ULL) ? 1 : 0;
}

// ---------------- convert float inputs to fp32 workspace (flattened grid) ----------------
__global__ void k_cvt(Ptrs ptrs, float* __restrict__ dst, const int* __restrict__ flag){
    long i4 = (long)blockIdx.x*256 + threadIdx.x;
    const long TOT4 = CVT_OFF.v[31]/4;
    if (i4 >= TOT4) return;
    long e = i4*4;
    int t = 0;
    #pragma unroll
    for(int i=1;i<31;i++) t += (e >= CVT_OFF.v[i]) ? 1 : 0;
    long l4 = i4 - CVT_OFF.v[t]/4;
    const void* src = ptrs.p[t];
    float4 o;
    if (*flag){
        ushort4 u = ((const ushort4*)src)[l4];
        o.x=b2f(u.x); o.y=b2f(u.y); o.z=b2f(u.z); o.w=b2f(u.w);
    } else {
        o = ((const float4*)src)[l4];
    }
    *(float4*)(dst + CVT_OFF.v[t] + l4*4) = o;
}

// ======== WT precompute: 24 H×H matrices -> bf16, FRAGMENT-MAJOR per 32-k chunk ========
// [0..11]=Wa_main(d,k), [12..14]=Wu2[:H], [15..17]=Wu1[:H], [18..20]=Wu1[H:2H], [21..23]=Wzm1
// Layout per (mi, k0/32) chunk (8192 u16 = 16KB):
//   idx = nt*512 + quad*128 + l15*8 + j  <-  src[k0 + quad*8 + j][nt*16 + l15]
__global__ void k_wt(const float* __restrict__ Wam, const float* __restrict__ Wu2,
                     const float* __restrict__ Wu1, const float* __restrict__ Wzm1,
                     u16* __restrict__ WT){
    int mi = blockIdx.z;
    const float* src;
    if (mi<12)      src = Wam  + (size_t)mi*H_*H_;
    else if (mi<15) src = Wu2  + (size_t)(mi-12)*(H_+6)*H_;
    else if (mi<18) src = Wu1  + (size_t)(mi-15)*2*H_*H_;
    else if (mi<21) src = Wu1  + (size_t)(mi-18)*2*H_*H_ + (size_t)H_*H_;
    else            src = Wzm1 + (size_t)(mi-21)*H_*H_;
    __shared__ float t[32][33];
    int x = threadIdx.x, y = threadIdx.y;
    int k0 = blockIdx.y*32, n0 = blockIdx.x*32;
    for(int yy=y; yy<32; yy+=8) t[yy][x] = src[(size_t)(k0+yy)*H_ + n0+x];
    __syncthreads();
    u16* dst = WT + ((size_t)mi*8 + (k0>>5))*8192;
    int quad = x>>3, j = x&7;           // kk = x = quad*8+j
    for(int yy=y; yy<32; yy+=8){
        int n = n0+yy, nt = n>>4, lv = n&15;
        dst[nt*512 + quad*128 + lv*8 + j] = f2b(t[x][yy]);
    }
}

// ---------------- vertex embedding: 8 rows per block ----------------
__global__ void k_embed(const u16* __restrict__ atom, const float* __restrict__ Wv,
                        const float* __restrict__ bv, float* __restrict__ vf,
                        u16* __restrict__ vf_bf, const int* __restrict__ flag){
    __shared__ float arow[8][A_];
    int r0 = blockIdx.x*8; int j = threadIdx.x;
    int fl = *flag;
    for(int i=j;i<8*A_;i+=256){
        int r=i/A_, a=i-r*A_;
        arow[r][a] = fl ? b2f(atom[(size_t)(r0+r)*A_+a])
                        : ((const float*)atom)[(size_t)(r0+r)*A_+a];
    }
    __syncthreads();
    float acc[8];
    float bj = bv[j];
    #pragma unroll
    for(int r=0;r<8;r++) acc[r]=bj;
    for(int a=0;a<A_;a++){
        float w = Wv[a*H_+j];
        #pragma unroll
        for(int r=0;r<8;r++) acc[r] += arow[r][a]*w;
    }
    #pragma unroll
    for(int r=0;r<8;r++){
        float v = acc[r];
        v = v>0.f ? v : 0.01f*v;
        vf[(size_t)(r0+r)*H_+j] = v;
        vf_bf[(size_t)(r0+r)*H_+j] = f2b(v);
    }
}

// ---------------- sf0 ----------------
__global__ void k_sf0(const float* __restrict__ vf, const float* __restrict__ dmask,
                      float* __restrict__ sf){
    int b = blockIdx.x, h = threadIdx.x;
    __shared__ float mk[N_];
    for(int n=threadIdx.x;n<N_;n+=256) mk[n] = dmask[b*N_+n];
    __syncthreads();
    float s=0.f;
    #pragma unroll 8
    for(int n=0;n<N_;n++) s += mk[n]*vf[((size_t)b*N_+n)*H_ + h];
    sf[b*H_+h]=s;
}

// ======== S1: batched GEMV from sf: asw(0..3), s2m(4), ssf(5), st(6 = s2m@Wzm2) ========
__global__ void k_s1(int d, const float* __restrict__ sf,
    const float* __restrict__ Was, const float* __restrict__ bas,
    const float* __restrict__ Wbmm,
    const float* __restrict__ Ws2m, const float* __restrict__ bs2m,
    const float* __restrict__ Wsup, const float* __restrict__ bsup,
    const float* __restrict__ Wzm2, const float* __restrict__ bzm2,
    float* __restrict__ asw, float* __restrict__ s2m, float* __restrict__ ssf,
    float* __restrict__ st)
{
    int b = blockIdx.x, m = blockIdx.y, j = threadIdx.x;
    __shared__ float sfl[H_];
    __shared__ float s2l[H_];
    sfl[j] = sf[b*H_+j];
    __syncthreads();
    if (m == 6){
        // stage 1: s2m_local (identical expression/order to seg m==4)
        const float* W = Ws2m + (size_t)d*H_*H_;
        float acc = bs2m[d*H_+j];
        #pragma unroll 8
        for(int h=0;h<H_;h++) acc += sfl[h]*W[h*H_+j];
        s2l[j] = tanhf(acc);
        __syncthreads();
        // stage 2: st = bzm2 + s2m @ Wzm2  (order == old partial scheme: bzm2 then h ascending)
        const float* W2 = Wzm2 + (size_t)d*H_*H_;
        float acc2 = bzm2[d*H_+j];
        #pragma unroll 8
        for(int h=0;h<H_;h++) acc2 += s2l[h]*W2[h*H_+j];
        st[b*H_+j] = acc2;
        return;
    }
    const float* W; float bias;
    if (m < 4){ W = Was + (size_t)(d*K_+m)*H_*H_; bias = bas[(d*K_+m)*H_+j]; }
    else if (m==4){ W = Ws2m + (size_t)d*H_*H_; bias = bs2m[d*H_+j]; }
    else { W = Wsup + (size_t)d*H_*H_; bias = bsup[d*H_+j]; }
    float acc = bias;
    #pragma unroll 8
    for(int h=0;h<H_;h++) acc += sfl[h]*W[h*H_+j];
    float v = tanhf(acc);
    if (m < 4) asw[(b*K_+m)*H_+j] = v * Wbmm[(d*K_+m)*H_+j];
    else if (m==4) s2m[b*H_+j] = v;
    else ssf[b*H_+j] = v;
}

// ======== async W staging: one 16KB chunk, linear, 4×16B DMA per thread ========
__device__ __forceinline__ void stageW(const u16* __restrict__ g, u16* l){
    int t = threadIdx.x;
    const u16* gs = g + t*8;
    u16* ls = l + t*8;
    #pragma unroll
    for(int it=0; it<4; ++it)
        __builtin_amdgcn_global_load_lds(
            (const __attribute__((address_space(1))) void*)(gs + it*2048),
            (__attribute__((address_space(3))) void*)(ls + it*2048),
            16, 0, 0);
}

// ================= 64-row MFMA core: A in regs (rolling 4-deep), W via global_load_lds dbuf =================
__device__ __forceinline__ void gemm_ldsW(const u16* __restrict__ Abf,
                                          const u16* __restrict__ WTg,
                                          u16* Wlds, f32x4 acc[2][8])
{
    int tid = threadIdx.x;
    int lane = tid & 63, wave = tid >> 6;
    int wy = wave >> 1, wx = wave & 1;
    int quad = lane >> 4, l15 = lane & 15;
    const u16* aP0 = Abf + (size_t)(wy*32 + l15)*H_ + quad*8;
    const u16* aP1 = aP0 + 16*H_;
    bf16x8 a[4][2];
    #pragma unroll
    for(int s=0;s<3;s++){
        a[s][0] = *(const bf16x8*)(aP0 + s*32);
        a[s][1] = *(const bf16x8*)(aP1 + s*32);
    }
    stageW(WTg, Wlds);
    #pragma unroll
    for(int mt=0;mt<2;mt++)
        #pragma unroll
        for(int nt=0;nt<8;nt++) acc[mt][nt]=(f32x4){0.f,0.f,0.f,0.f};
    __syncthreads();
    #pragma unroll
    for(int s=0;s<8;s++){
        if (s<7) stageW(WTg + (size_t)(s+1)*8192, Wlds + ((s+1)&1)*8192);
        if (s<5){
            int sl = s+3;
            a[sl&3][0] = *(const bf16x8*)(aP0 + sl*32);
            a[sl&3][1] = *(const bf16x8*)(aP1 + sl*32);
        }
        const u16* wb = Wlds + (s&1)*8192 + wx*4096 + quad*128 + l15*8;
        bf16x8 w[8];
        #pragma unroll
        for(int nt=0;nt<8;nt++) w[nt] = *(const bf16x8*)(wb + nt*512);
        #pragma unroll
        for(int mt=0;mt<2;mt++)
            #pragma unroll
            for(int nt=0;nt<8;nt++)
                acc[mt][nt] = __builtin_amdgcn_mfma_f32_16x16x32_bf16(
                    a[s&3][mt], w[nt], acc[mt][nt], 0,0,0);
        __syncthreads();
    }
}

// ================= 64-row MFMA core: A from (XOR-swizzled, stride-256) LDS tile =================
__device__ __forceinline__ void gemm_lds2(const u16* Als, const u16* __restrict__ WTg,
                                          u16* Wlds, f32x4 acc[2][8])
{
    int tid = threadIdx.x;
    int lane = tid & 63, wave = tid >> 6;
    int wy = wave >> 1, wx = wave & 1;
    int quad = lane >> 4, l15 = lane & 15;
    stageW(WTg, Wlds);
    #pragma unroll
    for(int mt=0;mt<2;mt++)
        #pragma unroll
        for(int nt=0;nt<8;nt++) acc[mt][nt]=(f32x4){0.f,0.f,0.f,0.f};
    __syncthreads();    // covers tile writes + W chunk0 DMA
    int r0 = wy*32 + l15, r1 = r0 + 16;
    #pragma unroll
    for(int s=0;s<8;s++){
        if (s<7) stageW(WTg + (size_t)(s+1)*8192, Wlds + ((s+1)&1)*8192);
        int c0 = s*32 + quad*8;
        bf16x8 a0 = *(const bf16x8*)(Als + r0*256 + (c0 ^ ((r0&7)<<3)));
        bf16x8 a1 = *(const bf16x8*)(Als + r1*256 + (c0 ^ ((r1&7)<<3)));
        const u16* wb = Wlds + (s&1)*8192 + wx*4096 + quad*128 + l15*8;
        bf16x8 w[8];
        #pragma unroll
        for(int nt=0;nt<8;nt++) w[nt] = *(const bf16x8*)(wb + nt*512);
        #pragma unroll
        for(int nt=0;nt<8;nt++){
            acc[0][nt] = __builtin_amdgcn_mfma_f32_16x16x32_bf16(a0, w[nt], acc[0][nt], 0,0,0);
            acc[1][nt] = __builtin_amdgcn_mfma_f32_16x16x32_bf16(a1, w[nt], acc[1][nt], 0,0,0);
        }
        __syncthreads();
    }
}

// ================= big GEMM over vf (bf16 A), 64-row tiles (proven best) =================
__global__ __launch_bounds__(256,3) void k_gemm_big(int d, const u16* __restrict__ vf_bf,
    const u16* __restrict__ WT, const float* __restrict__ ba_main,
    const float* __restrict__ bbmm, const float* __restrict__ bu1,
    const float* __restrict__ asw, float* __restrict__ score,
    float* __restrict__ proj_u2, float* __restrict__ pu1a)
{
    __shared__ __attribute__((aligned(16))) u16 Wlds[2*8192];
    int m0 = blockIdx.x*64;
    int seg = blockIdx.y;
    int b = m0 >> 9;
    int mi;
    if (seg < 4)      mi = d*4+seg;
    else if (seg==4)  mi = 12+d;
    else              mi = 15+d;
    f32x4 acc[2][8];
    gemm_ldsW(vf_bf + (size_t)m0*H_, WT + (size_t)mi*H_*H_, Wlds, acc);
    int tid=threadIdx.x, lane=tid&63, wave=tid>>6;
    int wy=wave>>1, wx=wave&1, quad=lane>>4, l15=lane&15;
    if (seg < 4){
        float* sred = (float*)Wlds;   // alias: loop done (post-barrier)
        const float* aswp = asw + (size_t)(b*K_+seg)*H_;
        const float* bap  = ba_main + (size_t)(d*K_+seg)*H_;
        float bbv[8], awv[8];
        #pragma unroll
        for(int nt=0;nt<8;nt++){
            int col = wx*128+nt*16+l15;
            bbv[nt]=bap[col]; awv[nt]=aswp[col];
        }
        #pragma unroll
        for(int mt=0;mt<2;mt++)
            #pragma unroll
            for(int r=0;r<4;r++){
                float p=0.f;
                #pragma unroll
                for(int nt=0;nt<8;nt++)
                    p += tanhf(acc[mt][nt][r]+bbv[nt])*awv[nt];
                int row = wy*32+mt*16+quad*4+r;
                sred[row*33 + wx*16+l15] = p;
            }
        __syncthreads();
        if (tid < 64){
            float s=0.f;
            #pragma unroll 8
            for(int i=0;i<32;i++) s += sred[tid*33+i];
            score[(size_t)(b*K_+seg)*N_ + (m0&511) + tid] = s + bbmm[d*K_+seg];
        }
    } else if (seg==4){
        #pragma unroll
        for(int mt=0;mt<2;mt++)
            #pragma unroll
            for(int nt=0;nt<8;nt++){
                int col = wx*128+nt*16+l15;
                #pragma unroll
                for(int r=0;r<4;r++){
                    int row = m0 + wy*32+mt*16+quad*4+r;
                    proj_u2[(size_t)row*H_+col] = acc[mt][nt][r];
                }
            }
    } else {
        const float* bp = bu1 + d*H_;
        #pragma unroll
        for(int mt=0;mt<2;mt++)
            #pragma unroll
            for(int nt=0;nt<8;nt++){
                int col = wx*128+nt*16+l15;
                float bb = bp[col];
                #pragma unroll
                for(int r=0;r<4;r++){
                    int row = m0 + wy*32+mt*16+quad*4+r;
                    pu1a[(size_t)row*H_+col] = acc[mt][nt][r] + bb;
                }
            }
    }
}

// ===== FUSED: main_self GEMM + z_main GEMM + GRU vf update =====
// GEMM1: A = nei (bf16, global). Epilogue1: ms = lrelu(acc + pu1a) kept in regs;
// ms_bf bits -> swizzled LDS tile. GEMM2: A = ms_lds. Epilogue2: GRU update.
__global__ __launch_bounds__(256,2) void k_msup(int d, const u16* __restrict__ neims,
    const u16* __restrict__ WT, const float* __restrict__ pu1a,
    const float* __restrict__ bzm1, const float* __restrict__ st,
    const float* __restrict__ s2m, float* __restrict__ vf, u16* __restrict__ vf_bf)
{
    __shared__ __attribute__((aligned(16))) u16 Wlds[2*8192];
    __shared__ __attribute__((aligned(16))) u16 ms_lds[64*256];
    int m0 = blockIdx.x*64; int b = m0>>9;
    f32x4 acc[2][8];
    gemm_ldsW(neims + (size_t)m0*H_, WT + (size_t)(18+d)*H_*H_, Wlds, acc);
    int tid=threadIdx.x, lane=tid&63, wave=tid>>6;
    int wy=wave>>1, wx=wave&1, quad=lane>>4, l15=lane&15;
    // epilogue 1: main_self
    #pragma unroll
    for(int mt=0;mt<2;mt++)
        #pragma unroll
        for(int nt=0;nt<8;nt++){
            int col = wx*128+nt*16+l15;
            #pragma unroll
            for(int r=0;r<4;r++){
                int rl = wy*32+mt*16+quad*4+r;
                float v = acc[mt][nt][r] + pu1a[(size_t)(m0+rl)*H_+col];
                v = v>0.f? v : 0.1f*v;
                acc[mt][nt][r] = v;
                ms_lds[rl*256 + (col ^ ((rl&7)<<3))] = f2b(v);
            }
        }
    // GEMM2 over ms (A from LDS); leading barrier inside covers ms_lds writes
    f32x4 acc2[2][8];
    gemm_lds2(ms_lds, WT + (size_t)(21+d)*H_*H_, Wlds, acc2);
    #pragma unroll
    for(int mt=0;mt<2;mt++)
        #pragma unroll
        for(int nt=0;nt<8;nt++){
            int col = wx*128+nt*16+l15;
            float bz = bzm1[d*H_+col];
            float stv = st[b*H_+col];
            float sm = s2m[b*H_+col];
            #pragma unroll
            for(int r=0;r<4;r++){
                int row = m0 + wy*32+mt*16+quad*4+r;
                float z = sigmoidf_(acc2[mt][nt][r] + bz + stv);
                float msv = acc[mt][nt][r];
                float o = (1.f-z)*msv + z*sm;
                vf[(size_t)row*H_+col] = o;
                vf_bf[(size_t)row*H_+col] = f2b(o);
            }
        }
}

// ===== FUSED: masked softmax + t (attn@vf) + m1 (t@Wm) per (b,k) =====
__global__ __launch_bounds__(512) void k_att(int d, const float* __restrict__ score,
    const float* __restrict__ dmask, const float* __restrict__ vf,
    const float* __restrict__ Wm, const float* __restrict__ bm,
    float* __restrict__ m2s)
{
    int b = blockIdx.x, k = blockIdx.y, tid = threadIdx.x;
    __shared__ float at[N_];
    __shared__ float sh[256];
    __shared__ float tp[2][256];
    const float* a = score + (size_t)(b*K_+k)*N_;
    float v0=0.f, v1=0.f, e0=0.f, e1=0.f;
    if (tid < 256){ v0=a[tid]; v1=a[tid+256]; sh[tid]=fmaxf(v0,v1); }
    __syncthreads();
    for(int s=128;s>0;s>>=1){ if(tid<s) sh[tid]=fmaxf(sh[tid],sh[tid+s]); __syncthreads(); }
    float m = sh[0]; __syncthreads();
    if (tid < 256){
        e0 = expf(v0-m)*dmask[b*N_+tid];
        e1 = expf(v1-m)*dmask[b*N_+tid+256];
        sh[tid]=e0+e1;
    }
    __syncthreads();
    for(int s=128;s>0;s>>=1){ if(tid<s) sh[tid]+=sh[tid+s]; __syncthreads(); }
    float S = sh[0];
    float inv = 1.f/(S+1e-6f);
    float sumattn = S*inv;
    if (tid < 256){ at[tid]=e0*inv; at[tid+256]=e1*inv; }
    __syncthreads();
    // t partials: half 0 covers n in [0,256), half 1 covers [256,512)
    int h = tid & 255, half = tid >> 8;
    {
        float acc=0.f;
        const float* vfp = vf + ((size_t)b*N_ + half*256)*H_ + h;
        const float* atp = at + half*256;
        #pragma unroll 8
        for(int n=0;n<256;n++) acc += atp[n]*vfp[(size_t)n*H_];
        tp[half][h]=acc;
    }
    __syncthreads();
    // m1: m2s[j] = sumattn*bm[j] + sum_h (tp0[h]+tp1[h]) * Wm[h][j]  (h split across halves)
    {
        const float* W = Wm + (size_t)(d*K_+k)*H_*H_;
        float acc = (half==0) ? sumattn*bm[(d*K_+k)*H_+h] : 0.f;
        int h0 = half*128;
        #pragma unroll 8
        for(int t2=h0; t2<h0+128; t2++) acc += (tp[0][t2]+tp[1][t2])*W[(size_t)t2*H_+h];
        at[half*256+h]=acc;   // at[] free now; reuse for partial exchange
    }
    __syncthreads();
    if (tid < 256) m2s[(size_t)(b*K_+k)*H_+tid] = at[tid]+at[256+tid];
}

// ===== FUSED: m2 partials + mts + m3 (p1,p2) + sf GRU update, one block per b =====
// Bit-identical to the old k_m2 + k_fin pair: each c-partial is sum_h ascending
// over m2s[b][c]; mts acc order = bm2s + p0 + p1 + p2 + p3.
__global__ __launch_bounds__(512) void k_fin(int d, const float* __restrict__ m2s,
    const float* __restrict__ Wm2s, const float* __restrict__ bm2s,
    const float* __restrict__ ssf,
    const float* __restrict__ Wzs1, const float* __restrict__ Wzs2,
    const float* __restrict__ bzs1, const float* __restrict__ bzs2,
    float* __restrict__ sf)
{
    int b = blockIdx.x, tid = threadIdx.x;
    int j = tid & 255, g = tid >> 8;
    __shared__ float m2l[4][256];
    __shared__ float pc[4][256];
    __shared__ float mtsl[256], ssl[256], pp[2][256];
    for(int i=tid;i<4*256;i+=512)
        m2l[i>>8][i&255] = m2s[((size_t)(b*K_) + (i>>8))*H_ + (i&255)];
    if (g==1) ssl[j] = ssf[b*H_+j];
    __syncthreads();
    #pragma unroll
    for(int cc=0; cc<2; cc++){
        int c = g*2+cc;
        const float* W = Wm2s + (size_t)d*(K_*H_)*H_ + (size_t)(c*H_)*H_;
        float acc=0.f;
        #pragma unroll 8
        for(int h=0;h<H_;h++) acc += m2l[c][h]*W[h*H_+j];
        pc[c][j]=acc;
    }
    __syncthreads();
    if (g==0){
        float acc = bm2s[d*H_+j];
        #pragma unroll
        for(int c=0;c<4;c++) acc += pc[c][j];
        mtsl[j] = tanhf(acc);
    }
    __syncthreads();
    {
        const float* W = (g ? Wzs2 : Wzs1) + (size_t)d*H_*H_;
        const float* x = g ? mtsl : ssl;
        float acc = 0.f;
        #pragma unroll 8
        for(int h=0;h<H_;h++) acc += x[h]*W[h*H_+j];
        pp[g][j] = acc;
    }
    __syncthreads();
    if (g==0){
        float z = sigmoidf_(pp[0][j]+bzs1[d*H_+j]+pp[1][j]+bzs2[d*H_+j]);
        sf[b*H_+j] = (1.f-z)*ssl[j] + z*mtsl[j];
    }
}

// ---- nei: 4 rows per block, high occupancy (latency-bound gather needs TLP) ----
__global__ void k_nei(int d, const int* __restrict__ anb, const int* __restrict__ bnb,
    const float* __restrict__ nbm, const float* __restrict__ bond,
    const float* __restrict__ Wu2, const float* __restrict__ bu2,
    const float* __restrict__ proj_u2, u16* __restrict__ nei_bf)
{
    __shared__ float W2s[6][256];
    __shared__ float bfeat[4][NB_][6];
    __shared__ int ai[4][NB_]; __shared__ int bi[4][NB_]; __shared__ float mk[4][NB_];
    int r0 = blockIdx.x*4; int b = r0 >> 9; int h = threadIdx.x;
    const float* W2 = Wu2 + (size_t)d*(H_+6)*H_ + (size_t)H_*H_;
    for(int i=h;i<6*H_;i+=256) W2s[i>>8][i&255] = W2[i];
    if (h < 4*NB_){
        int r=h/NB_, jn=h-r*NB_;
        ai[r][jn]=anb[(size_t)(r0+r)*NB_+jn];
        bi[r][jn]=bnb[(size_t)(r0+r)*NB_+jn];
        mk[r][jn]=nbm[(size_t)(r0+r)*NB_+jn];
    }
    __syncthreads();
    if (h < 4*NB_*6){
        int r=h/(NB_*6), rem=h-r*(NB_*6), jn=rem/6, i=rem-jn*6;
        bfeat[r][jn][i]=bond[((size_t)b*E_+bi[r][jn])*6+i];
    }
    __syncthreads();
    float bu = bu2[d*H_+h];
    #pragma unroll
    for(int r=0;r<4;r++){
        float acc=0.f;
        #pragma unroll
        for(int jn=0;jn<NB_;jn++){
            float v = proj_u2[((size_t)b*N_+ai[r][jn])*H_+h] + bu;
            #pragma unroll
            for(int i=0;i<6;i++) v += bfeat[r][jn][i]*W2s[i][h];
            v = v>0.f? v : 0.1f*v;
            acc += mk[r][jn]*v;
        }
        nei_bf[(size_t)(r0+r)*H_+h]=f2b(acc);
    }
}

// ---------------- final output ----------------
__global__ void k_out(const float* __restrict__ vf, const float* __restrict__ sf,
                      void* __restrict__ out, const int* __restrict__ flag){
    int idx = blockIdx.x*256 + threadIdx.x;
    const int total = M_*H_ + B_*H_;
    if (idx >= total) return;
    float v = (idx < M_*H_) ? vf[idx] : sf[idx - M_*H_];
    if (*flag) ((unsigned short*)out)[idx] = f2b(v);
    else       ((float*)out)[idx] = v;
}

extern "C" void kernel_launch(void* const* d_in, const int* in_sizes, int n_in,
                              void* d_out, int out_size, void* d_ws, size_t ws_size,
                              hipStream_t stream)
{
    const int* anb = (const int*)d_in[2];
    const int* bnb = (const int*)d_in[3];

    float* ws   = (float*)d_ws;
    int*   flag = (int*)ws;                 // 256 B reserved
    float* cvt  = ws + 64;
    float* p    = cvt + ((CVT_OFF.v[31] + 63) & ~63L);
    float* vf        = p; p += (size_t)M_*H_;
    float* proj_u2   = p; p += (size_t)M_*H_;
    float* pu1a      = p; p += (size_t)M_*H_;
    u16*   vf_bf     = (u16*)p; p += (size_t)M_*H_/2;
    u16*   neims     = (u16*)p; p += (size_t)M_*H_/2;
    float* sf        = p; p += B_*H_;
    float* score     = p; p += B_*K_*N_;
    float* asw       = p; p += B_*K_*H_;
    float* s2m       = p; p += B_*H_;
    float* ssf       = p; p += B_*H_;
    float* st        = p; p += B_*H_;
    float* m2s       = p; p += B_*K_*H_;
    u16*   WT        = (u16*)p;             // 24 * H*H bf16 = 3.1 MB

    const float* cBond = cvt + CVT_OFF.v[0];
    const float* cNbm  = cvt + CVT_OFF.v[1];
    const float* cDm   = cvt + CVT_OFF.v[2];
    const float* cWv   = cvt + CVT_OFF.v[3];
    const float* cbv   = cvt + CVT_OFF.v[4];
    const float* cWam  = cvt + CVT_OFF.v[5];
    const float* cbam  = cvt + CVT_OFF.v[6];
    const float* cWas  = cvt + CVT_OFF.v[7];
    const float* cbas  = cvt + CVT_OFF.v[8];
    const float* cWm   = cvt + CVT_OFF.v[9];
    const float* cbm   = cvt + CVT_OFF.v[10];
    const float* cWbmm = cvt + CVT_OFF.v[11];
    const float* cbbmm = cvt + CVT_OFF.v[12];
    const float* cWm2s = cvt + CVT_OFF.v[13];
    const float* cbm2s = cvt + CVT_OFF.v[14];
    const float* cWs2m = cvt + CVT_OFF.v[15];
    const float* cbs2m = cvt + CVT_OFF.v[16];
    const float* cWsup = cvt + CVT_OFF.v[17];
    const float* cbsup = cvt + CVT_OFF.v[18];
    const float* cWzm1 = cvt + CVT_OFF.v[19];
    const float* cbzm1 = cvt + CVT_OFF.v[20];
    const float* cWzm2 = cvt + CVT_OFF.v[21];
    const float* cbzm2 = cvt + CVT_OFF.v[22];
    const float* cWzs1 = cvt + CVT_OFF.v[23];
    const float* cbzs1 = cvt + CVT_OFF.v[24];
    const float* cWzs2 = cvt + CVT_OFF.v[25];
    const float* cbzs2 = cvt + CVT_OFF.v[26];
    const float* cWu2  = cvt + CVT_OFF.v[27];
    const float* cbu2  = cvt + CVT_OFF.v[28];
    const float* cWu1  = cvt + CVT_OFF.v[29];
    const float* cbu1  = cvt + CVT_OFF.v[30];

    Ptrs ptrs;
    {
        int idx[31] = {1,4,5,6,7,8,9,10,11,12,13,14,15,16,17,18,19,20,21,
                       22,23,24,25,26,27,28,29,30,31,32,33};
        for(int i=0;i<31;i++) ptrs.p[i] = d_in[idx[i]];
    }

    k_detect<<<1,64,0,stream>>>((const unsigned short*)d_in[6], flag);
    {
        long tot4 = CVT_OFF.v[31]/4;
        int gx = (int)((tot4 + 255)/256);
        k_cvt<<<gx,256,0,stream>>>(ptrs, cvt, flag);
    }
    k_wt<<<dim3(8,8,24),dim3(32,8),0,stream>>>(cWam, cWu2, cWu1, cWzm1, WT);

    k_embed<<<M_/8,256,0,stream>>>((const u16*)d_in[0], cWv, cbv, vf, vf_bf, flag);
    k_sf0<<<B_,256,0,stream>>>(vf, cDm, sf);
    for(int d=0; d<D_; d++){
        k_s1<<<dim3(B_,7),256,0,stream>>>(d, sf, cWas, cbas, cWbmm,
                                          cWs2m, cbs2m, cWsup, cbsup,
                                          cWzm2, cbzm2, asw, s2m, ssf, st);
        k_gemm_big<<<dim3(M_/64,6),256,0,stream>>>(d, vf_bf, WT, cbam, cbbmm, cbu1,
                                                   asw, score, proj_u2, pu1a);
        k_att<<<dim3(B_,K_),512,0,stream>>>(d, score, cDm, vf, cWm, cbm, m2s);
        k_nei<<<M_/4,256,0,stream>>>(d, anb, bnb, cNbm, cBond, cWu2, cbu2, proj_u2, neims);
        k_msup<<<M_/64,256,0,stream>>>(d, neims, WT, pu1a, cbzm1, st, s2m, vf, vf_bf);
        k_fin<<<B_,512,0,stream>>>(d, m2s, cWm2s, cbm2s, ssf, cWzs1, cWzs2, cbzs1, cbzs2, sf);
    }
    k_out<<<(M_*H_+B_*H_+255)/256,256,0,stream>>>(vf, sf, d_out, flag);
}

// Round 12
// 651.961 us; speedup vs baseline: 1.0570x; 1.0570x over previous
//
#include <hip/hip_runtime.h>
#include <hip/hip_bf16.h>

#define B_ 32
#define N_ 512
#define NB_ 10
#define E_ 1024
#define H_ 256
#define A_ 82
#define K_ 4
#define D_ 3
#define M_ (B_*N_)   // 16384 rows

typedef unsigned short u16;
typedef __attribute__((ext_vector_type(8))) short bf16x8;
typedef __attribute__((ext_vector_type(4))) float f32x4;

__device__ __forceinline__ float b2f(u16 u){
    unsigned int x = ((unsigned int)u) << 16;
    return __builtin_bit_cast(float, x);
}
__device__ __forceinline__ u16 f2b(float f){
    unsigned int x = __builtin_bit_cast(unsigned int, f);
    unsigned int lsb = (x >> 16) & 1u;
    x += 0x7fffu + lsb;
    return (u16)(x >> 16);
}
__device__ __forceinline__ float sigmoidf_(float x){ return 1.f/(1.f+expf(-x)); }

// ---- conversion table: 31 float tensors (atom excluded; ints excluded) ----
static constexpr int CVT_N[31] = {
    B_*E_*6, B_*N_*NB_, B_*N_,
    A_*H_, H_,
    D_*K_*H_*H_, D_*K_*H_, D_*K_*H_*H_, D_*K_*H_,
    D_*K_*H_*H_, D_*K_*H_, D_*K_*H_, D_*K_,
    D_*K_*H_*H_, D_*H_, D_*H_*H_, D_*H_,
    D_*H_*H_, D_*H_, D_*H_*H_, D_*H_,
    D_*H_*H_, D_*H_, D_*H_*H_, D_*H_,
    D_*H_*H_, D_*H_, D_*(H_+6)*H_, D_*H_,
    D_*2*H_*H_, D_*H_
};
struct Offs { long v[32]; };
static constexpr Offs mk_offs(){
    Offs o{}; o.v[0]=0;
    for(int i=0;i<31;i++) o.v[i+1]=o.v[i]+CVT_N[i];
    return o;
}
static constexpr Offs CVT_OFF = mk_offs();

struct Ptrs { const void* p[31]; };

// ---------------- dtype detection: bf16 vs f32 ----------------
__global__ void k_detect(const unsigned short* __restrict__ wv_raw, int* __restrict__ flag){
    float v = b2f(wv_raw[threadIdx.x]);
    bool plaus = (v==v) && (fabsf(v) < 100.0f);
    unsigned long long m = __ballot(plaus);
    if (threadIdx.x==0) *flag = (m == ~0ULL) ? 1 : 0;
}

// ---------------- convert float inputs to fp32 workspace (flattened grid) ----------------
__global__ void k_cvt(Ptrs ptrs, float* __restrict__ dst, const int* __restrict__ flag){
    long i4 = (long)blockIdx.x*256 + threadIdx.x;
    const long TOT4 = CVT_OFF.v[31]/4;
    if (i4 >= TOT4) return;
    long e = i4*4;
    int t = 0;
    #pragma unroll
    for(int i=1;i<31;i++) t += (e >= CVT_OFF.v[i]) ? 1 : 0;
    long l4 = i4 - CVT_OFF.v[t]/4;
    const void* src = ptrs.p[t];
    float4 o;
    if (*flag){
        ushort4 u = ((const ushort4*)src)[l4];
        o.x=b2f(u.x); o.y=b2f(u.y); o.z=b2f(u.z); o.w=b2f(u.w);
    } else {
        o = ((const float4*)src)[l4];
    }
    *(float4*)(dst + CVT_OFF.v[t] + l4*4) = o;
}

// ======== WT precompute: 24 H×H matrices -> bf16, FRAGMENT-MAJOR per 32-k chunk ========
// [0..11]=Wa_main(d,k), [12..14]=Wu2[:H], [15..17]=Wu1[:H], [18..20]=Wu1[H:2H], [21..23]=Wzm1
// Layout per (mi, k0/32) chunk (8192 u16 = 16KB):
//   idx = nt*512 + quad*128 + l15*8 + j  <-  src[k0 + quad*8 + j][nt*16 + l15]
__global__ void k_wt(const float* __restrict__ Wam, const float* __restrict__ Wu2,
                     const float* __restrict__ Wu1, const float* __restrict__ Wzm1,
                     u16* __restrict__ WT){
    int mi = blockIdx.z;
    const float* src;
    if (mi<12)      src = Wam  + (size_t)mi*H_*H_;
    else if (mi<15) src = Wu2  + (size_t)(mi-12)*(H_+6)*H_;
    else if (mi<18) src = Wu1  + (size_t)(mi-15)*2*H_*H_;
    else if (mi<21) src = Wu1  + (size_t)(mi-18)*2*H_*H_ + (size_t)H_*H_;
    else            src = Wzm1 + (size_t)(mi-21)*H_*H_;
    __shared__ float t[32][33];
    int x = threadIdx.x, y = threadIdx.y;
    int k0 = blockIdx.y*32, n0 = blockIdx.x*32;
    for(int yy=y; yy<32; yy+=8) t[yy][x] = src[(size_t)(k0+yy)*H_ + n0+x];
    __syncthreads();
    u16* dst = WT + ((size_t)mi*8 + (k0>>5))*8192;
    int quad = x>>3, j = x&7;           // kk = x = quad*8+j
    for(int yy=y; yy<32; yy+=8){
        int n = n0+yy, nt = n>>4, lv = n&15;
        dst[nt*512 + quad*128 + lv*8 + j] = f2b(t[x][yy]);
    }
}

// ---------------- vertex embedding: 8 rows per block ----------------
__global__ void k_embed(const u16* __restrict__ atom, const float* __restrict__ Wv,
                        const float* __restrict__ bv, float* __restrict__ vf,
                        u16* __restrict__ vf_bf, const int* __restrict__ flag){
    __shared__ float arow[8][A_];
    int r0 = blockIdx.x*8; int j = threadIdx.x;
    int fl = *flag;
    for(int i=j;i<8*A_;i+=256){
        int r=i/A_, a=i-r*A_;
        arow[r][a] = fl ? b2f(atom[(size_t)(r0+r)*A_+a])
                        : ((const float*)atom)[(size_t)(r0+r)*A_+a];
    }
    __syncthreads();
    float acc[8];
    float bj = bv[j];
    #pragma unroll
    for(int r=0;r<8;r++) acc[r]=bj;
    for(int a=0;a<A_;a++){
        float w = Wv[a*H_+j];
        #pragma unroll
        for(int r=0;r<8;r++) acc[r] += arow[r][a]*w;
    }
    #pragma unroll
    for(int r=0;r<8;r++){
        float v = acc[r];
        v = v>0.f ? v : 0.01f*v;
        vf[(size_t)(r0+r)*H_+j] = v;
        vf_bf[(size_t)(r0+r)*H_+j] = f2b(v);
    }
}

// ---------------- sf0 ----------------
__global__ void k_sf0(const float* __restrict__ vf, const float* __restrict__ dmask,
                      float* __restrict__ sf){
    int b = blockIdx.x, h = threadIdx.x;
    __shared__ float mk[N_];
    for(int n=threadIdx.x;n<N_;n+=256) mk[n] = dmask[b*N_+n];
    __syncthreads();
    float s=0.f;
    #pragma unroll 8
    for(int n=0;n<N_;n++) s += mk[n]*vf[((size_t)b*N_+n)*H_ + h];
    sf[b*H_+h]=s;
}

// ======== S1: batched GEMV from sf: asw(0..3), s2m(4), ssf(5), st(6 = s2m@Wzm2) ========
__global__ void k_s1(int d, const float* __restrict__ sf,
    const float* __restrict__ Was, const float* __restrict__ bas,
    const float* __restrict__ Wbmm,
    const float* __restrict__ Ws2m, const float* __restrict__ bs2m,
    const float* __restrict__ Wsup, const float* __restrict__ bsup,
    const float* __restrict__ Wzm2, const float* __restrict__ bzm2,
    float* __restrict__ asw, float* __restrict__ s2m, float* __restrict__ ssf,
    float* __restrict__ st)
{
    int b = blockIdx.x, m = blockIdx.y, j = threadIdx.x;
    __shared__ float sfl[H_];
    __shared__ float s2l[H_];
    sfl[j] = sf[b*H_+j];
    __syncthreads();
    if (m == 6){
        // stage 1: s2m_local (identical expression/order to seg m==4)
        const float* W = Ws2m + (size_t)d*H_*H_;
        float acc = bs2m[d*H_+j];
        #pragma unroll 8
        for(int h=0;h<H_;h++) acc += sfl[h]*W[h*H_+j];
        s2l[j] = tanhf(acc);
        __syncthreads();
        // stage 2: st = bzm2 + s2m @ Wzm2  (order == old partial scheme: bzm2 then h ascending)
        const float* W2 = Wzm2 + (size_t)d*H_*H_;
        float acc2 = bzm2[d*H_+j];
        #pragma unroll 8
        for(int h=0;h<H_;h++) acc2 += s2l[h]*W2[h*H_+j];
        st[b*H_+j] = acc2;
        return;
    }
    const float* W; float bias;
    if (m < 4){ W = Was + (size_t)(d*K_+m)*H_*H_; bias = bas[(d*K_+m)*H_+j]; }
    else if (m==4){ W = Ws2m + (size_t)d*H_*H_; bias = bs2m[d*H_+j]; }
    else { W = Wsup + (size_t)d*H_*H_; bias = bsup[d*H_+j]; }
    float acc = bias;
    #pragma unroll 8
    for(int h=0;h<H_;h++) acc += sfl[h]*W[h*H_+j];
    float v = tanhf(acc);
    if (m < 4) asw[(b*K_+m)*H_+j] = v * Wbmm[(d*K_+m)*H_+j];
    else if (m==4) s2m[b*H_+j] = v;
    else ssf[b*H_+j] = v;
}

// ======== async W staging: one 16KB chunk, linear, 4×16B DMA per thread ========
__device__ __forceinline__ void stageW(const u16* __restrict__ g, u16* l){
    int t = threadIdx.x;
    const u16* gs = g + t*8;
    u16* ls = l + t*8;
    #pragma unroll
    for(int it=0; it<4; ++it)
        __builtin_amdgcn_global_load_lds(
            (const __attribute__((address_space(1))) void*)(gs + it*2048),
            (__attribute__((address_space(3))) void*)(ls + it*2048),
            16, 0, 0);
}

// ================= MFMA core: A in registers (rolling 4-deep), W via global_load_lds dbuf =================
__device__ __forceinline__ void gemm_ldsW(const u16* __restrict__ Abf,
                                          const u16* __restrict__ WTg,
                                          u16* Wlds, f32x4 acc[2][8])
{
    int tid = threadIdx.x;
    int lane = tid & 63, wave = tid >> 6;
    int wy = wave >> 1, wx = wave & 1;
    int quad = lane >> 4, l15 = lane & 15;
    const u16* aP0 = Abf + (size_t)(wy*32 + l15)*H_ + quad*8;
    const u16* aP1 = aP0 + 16*H_;
    bf16x8 a[4][2];
    #pragma unroll
    for(int s=0;s<3;s++){
        a[s][0] = *(const bf16x8*)(aP0 + s*32);
        a[s][1] = *(const bf16x8*)(aP1 + s*32);
    }
    stageW(WTg, Wlds);
    #pragma unroll
    for(int mt=0;mt<2;mt++)
        #pragma unroll
        for(int nt=0;nt<8;nt++) acc[mt][nt]=(f32x4){0.f,0.f,0.f,0.f};
    __syncthreads();
    #pragma unroll
    for(int s=0;s<8;s++){
        if (s<7) stageW(WTg + (size_t)(s+1)*8192, Wlds + ((s+1)&1)*8192);
        if (s<5){
            int sl = s+3;
            a[sl&3][0] = *(const bf16x8*)(aP0 + sl*32);
            a[sl&3][1] = *(const bf16x8*)(aP1 + sl*32);
        }
        const u16* wb = Wlds + (s&1)*8192 + wx*4096 + quad*128 + l15*8;
        bf16x8 w[8];
        #pragma unroll
        for(int nt=0;nt<8;nt++) w[nt] = *(const bf16x8*)(wb + nt*512);
        #pragma unroll
        for(int mt=0;mt<2;mt++)
            #pragma unroll
            for(int nt=0;nt<8;nt++)
                acc[mt][nt] = __builtin_amdgcn_mfma_f32_16x16x32_bf16(
                    a[s&3][mt], w[nt], acc[mt][nt], 0,0,0);
        __syncthreads();
    }
}

// ================= MFMA core variant: A from (XOR-swizzled, stride-256) LDS tile =================
__device__ __forceinline__ void gemm_lds2(const u16* Als, const u16* __restrict__ WTg,
                                          u16* Wlds, f32x4 acc[2][8])
{
    int tid = threadIdx.x;
    int lane = tid & 63, wave = tid >> 6;
    int wy = wave >> 1, wx = wave & 1;
    int quad = lane >> 4, l15 = lane & 15;
    stageW(WTg, Wlds);
    #pragma unroll
    for(int mt=0;mt<2;mt++)
        #pragma unroll
        for(int nt=0;nt<8;nt++) acc[mt][nt]=(f32x4){0.f,0.f,0.f,0.f};
    __syncthreads();    // covers ms_lds writes + W chunk0 DMA
    int r0 = wy*32 + l15, r1 = r0 + 16;
    #pragma unroll
    for(int s=0;s<8;s++){
        if (s<7) stageW(WTg + (size_t)(s+1)*8192, Wlds + ((s+1)&1)*8192);
        int c0 = s*32 + quad*8;
        bf16x8 a0 = *(const bf16x8*)(Als + r0*256 + (c0 ^ ((r0&7)<<3)));
        bf16x8 a1 = *(const bf16x8*)(Als + r1*256 + (c0 ^ ((r1&7)<<3)));
        const u16* wb = Wlds + (s&1)*8192 + wx*4096 + quad*128 + l15*8;
        bf16x8 w[8];
        #pragma unroll
        for(int nt=0;nt<8;nt++) w[nt] = *(const bf16x8*)(wb + nt*512);
        #pragma unroll
        for(int nt=0;nt<8;nt++){
            acc[0][nt] = __builtin_amdgcn_mfma_f32_16x16x32_bf16(a0, w[nt], acc[0][nt], 0,0,0);
            acc[1][nt] = __builtin_amdgcn_mfma_f32_16x16x32_bf16(a1, w[nt], acc[1][nt], 0,0,0);
        }
        __syncthreads();
    }
}

// ================= big GEMM over vf (bf16 A) =================
__global__ __launch_bounds__(256,3) void k_gemm_big(int d, const u16* __restrict__ vf_bf,
    const u16* __restrict__ WT, const float* __restrict__ ba_main,
    const float* __restrict__ bbmm, const float* __restrict__ bu1,
    const float* __restrict__ asw, float* __restrict__ score,
    float* __restrict__ proj_u2, float* __restrict__ pu1a)
{
    __shared__ __attribute__((aligned(16))) u16 Wlds[2*8192];
    int m0 = blockIdx.x*64;
    int seg = blockIdx.y;
    int b = m0 >> 9;
    int mi;
    if (seg < 4)      mi = d*4+seg;
    else if (seg==4)  mi = 12+d;
    else              mi = 15+d;
    f32x4 acc[2][8];
    gemm_ldsW(vf_bf + (size_t)m0*H_, WT + (size_t)mi*H_*H_, Wlds, acc);
    int tid=threadIdx.x, lane=tid&63, wave=tid>>6;
    int wy=wave>>1, wx=wave&1, quad=lane>>4, l15=lane&15;
    if (seg < 4){
        float* sred = (float*)Wlds;   // alias: loop done (post-barrier)
        const float* aswp = asw + (size_t)(b*K_+seg)*H_;
        const float* bap  = ba_main + (size_t)(d*K_+seg)*H_;
        float bbv[8], awv[8];
        #pragma unroll
        for(int nt=0;nt<8;nt++){
            int col = wx*128+nt*16+l15;
            bbv[nt]=bap[col]; awv[nt]=aswp[col];
        }
        #pragma unroll
        for(int mt=0;mt<2;mt++)
            #pragma unroll
            for(int r=0;r<4;r++){
                float p=0.f;
                #pragma unroll
                for(int nt=0;nt<8;nt++)
                    p += tanhf(acc[mt][nt][r]+bbv[nt])*awv[nt];
                int row = wy*32+mt*16+quad*4+r;
                sred[row*33 + wx*16+l15] = p;
            }
        __syncthreads();
        if (tid < 64){
            float s=0.f;
            #pragma unroll 8
            for(int i=0;i<32;i++) s += sred[tid*33+i];
            score[(size_t)(b*K_+seg)*N_ + (m0&511) + tid] = s + bbmm[d*K_+seg];
        }
    } else if (seg==4){
        #pragma unroll
        for(int mt=0;mt<2;mt++)
            #pragma unroll
            for(int nt=0;nt<8;nt++){
                int col = wx*128+nt*16+l15;
                #pragma unroll
                for(int r=0;r<4;r++){
                    int row = m0 + wy*32+mt*16+quad*4+r;
                    proj_u2[(size_t)row*H_+col] = acc[mt][nt][r];
                }
            }
    } else {
        const float* bp = bu1 + d*H_;
        #pragma unroll
        for(int mt=0;mt<2;mt++)
            #pragma unroll
            for(int nt=0;nt<8;nt++){
                int col = wx*128+nt*16+l15;
                float bb = bp[col];
                #pragma unroll
                for(int r=0;r<4;r++){
                    int row = m0 + wy*32+mt*16+quad*4+r;
                    pu1a[(size_t)row*H_+col] = acc[mt][nt][r] + bb;
                }
            }
    }
}

// ===== FUSED: main_self GEMM + z_main GEMM + GRU vf update =====
// GEMM1: A = nei (bf16, global). Epilogue1: ms = lrelu(acc + pu1a) kept in regs;
// ms_bf bits -> swizzled LDS tile. GEMM2: A = ms_lds. Epilogue2: GRU update.
__global__ __launch_bounds__(256,2) void k_msup(int d, const u16* __restrict__ neims,
    const u16* __restrict__ WT, const float* __restrict__ pu1a,
    const float* __restrict__ bzm1, const float* __restrict__ st,
    const float* __restrict__ s2m, float* __restrict__ vf, u16* __restrict__ vf_bf)
{
    __shared__ __attribute__((aligned(16))) u16 Wlds[2*8192];
    __shared__ __attribute__((aligned(16))) u16 ms_lds[64*256];
    int m0 = blockIdx.x*64; int b = m0>>9;
    f32x4 acc[2][8];
    gemm_ldsW(neims + (size_t)m0*H_, WT + (size_t)(18+d)*H_*H_, Wlds, acc);
    int tid=threadIdx.x, lane=tid&63, wave=tid>>6;
    int wy=wave>>1, wx=wave&1, quad=lane>>4, l15=lane&15;
    // epilogue 1: main_self
    #pragma unroll
    for(int mt=0;mt<2;mt++)
        #pragma unroll
        for(int nt=0;nt<8;nt++){
            int col = wx*128+nt*16+l15;
            #pragma unroll
            for(int r=0;r<4;r++){
                int rl = wy*32+mt*16+quad*4+r;
                float v = acc[mt][nt][r] + pu1a[(size_t)(m0+rl)*H_+col];
                v = v>0.f? v : 0.1f*v;
                acc[mt][nt][r] = v;
                ms_lds[rl*256 + (col ^ ((rl&7)<<3))] = f2b(v);
            }
        }
    // GEMM2 over ms (A from LDS); leading barrier inside covers ms_lds writes
    f32x4 acc2[2][8];
    gemm_lds2(ms_lds, WT + (size_t)(21+d)*H_*H_, Wlds, acc2);
    #pragma unroll
    for(int mt=0;mt<2;mt++)
        #pragma unroll
        for(int nt=0;nt<8;nt++){
            int col = wx*128+nt*16+l15;
            float bz = bzm1[d*H_+col];
            float stv = st[b*H_+col];
            float sm = s2m[b*H_+col];
            #pragma unroll
            for(int r=0;r<4;r++){
                int row = m0 + wy*32+mt*16+quad*4+r;
                float z = sigmoidf_(acc2[mt][nt][r] + bz + stv);
                float msv = acc[mt][nt][r];
                float o = (1.f-z)*msv + z*sm;
                vf[(size_t)row*H_+col] = o;
                vf_bf[(size_t)row*H_+col] = f2b(o);
            }
        }
}

// ===== FUSED: masked softmax + t (attn@vf) + m1 (t@Wm) per (b,k) =====
__global__ __launch_bounds__(512) void k_att(int d, const float* __restrict__ score,
    const float* __restrict__ dmask, const float* __restrict__ vf,
    const float* __restrict__ Wm, const float* __restrict__ bm,
    float* __restrict__ m2s)
{
    int b = blockIdx.x, k = blockIdx.y, tid = threadIdx.x;
    __shared__ float at[N_];
    __shared__ float sh[256];
    __shared__ float tp[2][256];
    const float* a = score + (size_t)(b*K_+k)*N_;
    float v0=0.f, v1=0.f, e0=0.f, e1=0.f;
    if (tid < 256){ v0=a[tid]; v1=a[tid+256]; sh[tid]=fmaxf(v0,v1); }
    __syncthreads();
    for(int s=128;s>0;s>>=1){ if(tid<s) sh[tid]=fmaxf(sh[tid],sh[tid+s]); __syncthreads(); }
    float m = sh[0]; __syncthreads();
    if (tid < 256){
        e0 = expf(v0-m)*dmask[b*N_+tid];
        e1 = expf(v1-m)*dmask[b*N_+tid+256];
        sh[tid]=e0+e1;
    }
    __syncthreads();
    for(int s=128;s>0;s>>=1){ if(tid<s) sh[tid]+=sh[tid+s]; __syncthreads(); }
    float S = sh[0];
    float inv = 1.f/(S+1e-6f);
    float sumattn = S*inv;
    if (tid < 256){ at[tid]=e0*inv; at[tid+256]=e1*inv; }
    __syncthreads();
    // t partials: half 0 covers n in [0,256), half 1 covers [256,512)
    int h = tid & 255, half = tid >> 8;
    {
        float acc=0.f;
        const float* vfp = vf + ((size_t)b*N_ + half*256)*H_ + h;
        const float* atp = at + half*256;
        #pragma unroll 8
        for(int n=0;n<256;n++) acc += atp[n]*vfp[(size_t)n*H_];
        tp[half][h]=acc;
    }
    __syncthreads();
    // m1: m2s[j] = sumattn*bm[j] + sum_h (tp0[h]+tp1[h]) * Wm[h][j]  (h split across halves)
    {
        const float* W = Wm + (size_t)(d*K_+k)*H_*H_;
        float acc = (half==0) ? sumattn*bm[(d*K_+k)*H_+h] : 0.f;
        int h0 = half*128;
        #pragma unroll 8
        for(int t2=h0; t2<h0+128; t2++) acc += (tp[0][t2]+tp[1][t2])*W[(size_t)t2*H_+h];
        at[half*256+h]=acc;   // at[] free now; reuse for partial exchange
    }
    __syncthreads();
    if (tid < 256) m2s[(size_t)(b*K_+k)*H_+tid] = at[tid]+at[256+tid];
}

// ======== M2: mts partials ========
__global__ void k_m2(int d, const float* __restrict__ m2s, const float* __restrict__ Wm2s,
                     float* __restrict__ mtsp)
{
    int b=blockIdx.x, c=blockIdx.y, j=threadIdx.x;
    __shared__ float xl[H_];
    xl[j]=m2s[(size_t)(b*K_+c)*H_+j];
    __syncthreads();
    const float* W = Wm2s + (size_t)d*(K_*H_)*H_ + (size_t)(c*H_)*H_;
    float acc=0.f;
    #pragma unroll 8
    for(int h=0;h<H_;h++) acc += xl[h]*W[h*H_+j];
    mtsp[((size_t)c*B_+b)*H_+j]=acc;
}

// ===== FUSED: mts + m3 (p1,p2) + sf GRU update, one block per b =====
__global__ __launch_bounds__(512) void k_fin(int d, const float* __restrict__ mtsp,
    const float* __restrict__ bm2s, const float* __restrict__ ssf,
    const float* __restrict__ Wzs1, const float* __restrict__ Wzs2,
    const float* __restrict__ bzs1, const float* __restrict__ bzs2,
    float* __restrict__ sf)
{
    int b = blockIdx.x, tid = threadIdx.x;
    int j = tid & 255, g = tid >> 8;
    __shared__ float mtsl[256], ssl[256], pp[2][256];
    if (g==0){
        float acc = bm2s[d*H_+j];
        #pragma unroll
        for(int c=0;c<4;c++) acc += mtsp[((size_t)c*B_+b)*H_+j];
        mtsl[j] = tanhf(acc);
    } else {
        ssl[j] = ssf[b*H_+j];
    }
    __syncthreads();
    {
        const float* W = (g ? Wzs2 : Wzs1) + (size_t)d*H_*H_;
        const float* x = g ? mtsl : ssl;
        float acc = 0.f;
        #pragma unroll 8
        for(int h=0;h<H_;h++) acc += x[h]*W[h*H_+j];
        pp[g][j] = acc;
    }
    __syncthreads();
    if (g==0){
        float z = sigmoidf_(pp[0][j]+bzs1[d*H_+j]+pp[1][j]+bzs2[d*H_+j]);
        sf[b*H_+j] = (1.f-z)*ssl[j] + z*mtsl[j];
    }
}

// ---- nei: 4 rows per block, writes bf16 directly ----
__global__ void k_nei(int d, const int* __restrict__ anb, const int* __restrict__ bnb,
    const float* __restrict__ nbm, const float* __restrict__ bond,
    const float* __restrict__ Wu2, const float* __restrict__ bu2,
    const float* __restrict__ proj_u2, u16* __restrict__ nei_bf)
{
    __shared__ float W2s[6][256];
    __shared__ float bfeat[4][NB_][6];
    __shared__ int ai[4][NB_]; __shared__ int bi[4][NB_]; __shared__ float mk[4][NB_];
    int r0 = blockIdx.x*4; int b = r0 >> 9; int h = threadIdx.x;
    const float* W2 = Wu2 + (size_t)d*(H_+6)*H_ + (size_t)H_*H_;
    for(int i=h;i<6*H_;i+=256) W2s[i>>8][i&255] = W2[i];
    if (h < 4*NB_){
        int r=h/NB_, jn=h-r*NB_;
        ai[r][jn]=anb[(size_t)(r0+r)*NB_+jn];
        bi[r][jn]=bnb[(size_t)(r0+r)*NB_+jn];
        mk[r][jn]=nbm[(size_t)(r0+r)*NB_+jn];
    }
    __syncthreads();
    if (h < 4*NB_*6){
        int r=h/(NB_*6), rem=h-r*(NB_*6), jn=rem/6, i=rem-jn*6;
        bfeat[r][jn][i]=bond[((size_t)b*E_+bi[r][jn])*6+i];
    }
    __syncthreads();
    float bu = bu2[d*H_+h];
    #pragma unroll
    for(int r=0;r<4;r++){
        float acc=0.f;
        #pragma unroll
        for(int jn=0;jn<NB_;jn++){
            float v = proj_u2[((size_t)b*N_+ai[r][jn])*H_+h] + bu;
            #pragma unroll
            for(int i=0;i<6;i++) v += bfeat[r][jn][i]*W2s[i][h];
            v = v>0.f? v : 0.1f*v;
            acc += mk[r][jn]*v;
        }
        nei_bf[(size_t)(r0+r)*H_+h]=f2b(acc);
    }
}

// ---------------- final output ----------------
__global__ void k_out(const float* __restrict__ vf, const float* __restrict__ sf,
                      void* __restrict__ out, const int* __restrict__ flag){
    int idx = blockIdx.x*256 + threadIdx.x;
    const int total = M_*H_ + B_*H_;
    if (idx >= total) return;
    float v = (idx < M_*H_) ? vf[idx] : sf[idx - M_*H_];
    if (*flag) ((unsigned short*)out)[idx] = f2b(v);
    else       ((float*)out)[idx] = v;
}

extern "C" void kernel_launch(void* const* d_in, const int* in_sizes, int n_in,
                              void* d_out, int out_size, void* d_ws, size_t ws_size,
                              hipStream_t stream)
{
    const int* anb = (const int*)d_in[2];
    const int* bnb = (const int*)d_in[3];

    float* ws   = (float*)d_ws;
    int*   flag = (int*)ws;                 // 256 B reserved
    float* cvt  = ws + 64;
    float* p    = cvt + ((CVT_OFF.v[31] + 63) & ~63L);
    float* vf        = p; p += (size_t)M_*H_;
    float* proj_u2   = p; p += (size_t)M_*H_;
    float* pu1a      = p; p += (size_t)M_*H_;
    u16*   vf_bf     = (u16*)p; p += (size_t)M_*H_/2;
    u16*   neims     = (u16*)p; p += (size_t)M_*H_/2;
    float* sf        = p; p += B_*H_;
    float* score     = p; p += B_*K_*N_;
    float* asw       = p; p += B_*K_*H_;
    float* s2m       = p; p += B_*H_;
    float* ssf       = p; p += B_*H_;
    float* st        = p; p += B_*H_;
    float* m2s       = p; p += B_*K_*H_;
    float* mtsp      = p; p += 4*B_*H_;
    u16*   WT        = (u16*)p;             // 24 * H*H bf16 = 3.1 MB

    const float* cBond = cvt + CVT_OFF.v[0];
    const float* cNbm  = cvt + CVT_OFF.v[1];
    const float* cDm   = cvt + CVT_OFF.v[2];
    const float* cWv   = cvt + CVT_OFF.v[3];
    const float* cbv   = cvt + CVT_OFF.v[4];
    const float* cWam  = cvt + CVT_OFF.v[5];
    const float* cbam  = cvt + CVT_OFF.v[6];
    const float* cWas  = cvt + CVT_OFF.v[7];
    const float* cbas  = cvt + CVT_OFF.v[8];
    const float* cWm   = cvt + CVT_OFF.v[9];
    const float* cbm   = cvt + CVT_OFF.v[10];
    const float* cWbmm = cvt + CVT_OFF.v[11];
    const float* cbbmm = cvt + CVT_OFF.v[12];
    const float* cWm2s = cvt + CVT_OFF.v[13];
    const float* cbm2s = cvt + CVT_OFF.v[14];
    const float* cWs2m = cvt + CVT_OFF.v[15];
    const float* cbs2m = cvt + CVT_OFF.v[16];
    const float* cWsup = cvt + CVT_OFF.v[17];
    const float* cbsup = cvt + CVT_OFF.v[18];
    const float* cWzm1 = cvt + CVT_OFF.v[19];
    const float* cbzm1 = cvt + CVT_OFF.v[20];
    const float* cWzm2 = cvt + CVT_OFF.v[21];
    const float* cbzm2 = cvt + CVT_OFF.v[22];
    const float* cWzs1 = cvt + CVT_OFF.v[23];
    const float* cbzs1 = cvt + CVT_OFF.v[24];
    const float* cWzs2 = cvt + CVT_OFF.v[25];
    const float* cbzs2 = cvt + CVT_OFF.v[26];
    const float* cWu2  = cvt + CVT_OFF.v[27];
    const float* cbu2  = cvt + CVT_OFF.v[28];
    const float* cWu1  = cvt + CVT_OFF.v[29];
    const float* cbu1  = cvt + CVT_OFF.v[30];

    Ptrs ptrs;
    {
        int idx[31] = {1,4,5,6,7,8,9,10,11,12,13,14,15,16,17,18,19,20,21,
                       22,23,24,25,26,27,28,29,30,31,32,33};
        for(int i=0;i<31;i++) ptrs.p[i] = d_in[idx[i]];
    }

    k_detect<<<1,64,0,stream>>>((const unsigned short*)d_in[6], flag);
    {
        long tot4 = CVT_OFF.v[31]/4;
        int gx = (int)((tot4 + 255)/256);
        k_cvt<<<gx,256,0,stream>>>(ptrs, cvt, flag);
    }
    k_wt<<<dim3(8,8,24),dim3(32,8),0,stream>>>(cWam, cWu2, cWu1, cWzm1, WT);

    k_embed<<<M_/8,256,0,stream>>>((const u16*)d_in[0], cWv, cbv, vf, vf_bf, flag);
    k_sf0<<<B_,256,0,stream>>>(vf, cDm, sf);
    for(int d=0; d<D_; d++){
        k_s1<<<dim3(B_,7),256,0,stream>>>(d, sf, cWas, cbas, cWbmm,
                                          cWs2m, cbs2m, cWsup, cbsup,
                                          cWzm2, cbzm2, asw, s2m, ssf, st);
        k_gemm_big<<<dim3(M_/64,6),256,0,stream>>>(d, vf_bf, WT, cbam, cbbmm, cbu1,
                                                   asw, score, proj_u2, pu1a);
        k_att<<<dim3(B_,K_),512,0,stream>>>(d, score, cDm, vf, cWm, cbm, m2s);
        k_nei<<<M_/4,256,0,stream>>>(d, anb, bnb, cNbm, cBond, cWu2, cbu2, proj_u2, neims);
        k_msup<<<M_/64,256,0,stream>>>(d, neims, WT, pu1a, cbzm1, st, s2m, vf, vf_bf);
        k_m2<<<dim3(B_,4),256,0,stream>>>(d, m2s, cWm2s, mtsp);
        k_fin<<<B_,512,0,stream>>>(d, mtsp, cbm2s, ssf, cWzs1, cWzs2, cbzs1, cbzs2, sf);
    }
    k_out<<<(M_*H_+B_*H_+255)/256,256,0,stream>>>(vf, sf, d_out, flag);
}

// Round 15
// 645.518 us; speedup vs baseline: 1.0675x; 1.0100x over previous
//
#include <hip/hip_runtime.h>
#include <hip/hip_bf16.h>

#define B_ 32
#define N_ 512
#define NB_ 10
#define E_ 1024
#define H_ 256
#define A_ 82
#define K_ 4
#define D_ 3
#define M_ (B_*N_)   // 16384 rows

typedef unsigned short u16;
typedef __attribute__((ext_vector_type(8))) short bf16x8;
typedef __attribute__((ext_vector_type(4))) float f32x4;

__device__ __forceinline__ float b2f(u16 u){
    unsigned int x = ((unsigned int)u) << 16;
    return __builtin_bit_cast(float, x);
}
__device__ __forceinline__ u16 f2b(float f){
    unsigned int x = __builtin_bit_cast(unsigned int, f);
    unsigned int lsb = (x >> 16) & 1u;
    x += 0x7fffu + lsb;
    return (u16)(x >> 16);
}
__device__ __forceinline__ float sigmoidf_(float x){ return 1.f/(1.f+expf(-x)); }

// ---- conversion table: 31 float tensors (atom excluded; ints excluded) ----
static constexpr int CVT_N[31] = {
    B_*E_*6, B_*N_*NB_, B_*N_,
    A_*H_, H_,
    D_*K_*H_*H_, D_*K_*H_, D_*K_*H_*H_, D_*K_*H_,
    D_*K_*H_*H_, D_*K_*H_, D_*K_*H_, D_*K_,
    D_*K_*H_*H_, D_*H_, D_*H_*H_, D_*H_,
    D_*H_*H_, D_*H_, D_*H_*H_, D_*H_,
    D_*H_*H_, D_*H_, D_*H_*H_, D_*H_,
    D_*H_*H_, D_*H_, D_*(H_+6)*H_, D_*H_,
    D_*2*H_*H_, D_*H_
};
struct Offs { long v[32]; };
static constexpr Offs mk_offs(){
    Offs o{}; o.v[0]=0;
    for(int i=0;i<31;i++) o.v[i+1]=o.v[i]+CVT_N[i];
    return o;
}
static constexpr Offs CVT_OFF = mk_offs();

struct Ptrs { const void* p[31]; };

// ---------------- dtype detection: bf16 vs f32 ----------------
__global__ void k_detect(const unsigned short* __restrict__ wv_raw, int* __restrict__ flag){
    float v = b2f(wv_raw[threadIdx.x]);
    bool plaus = (v==v) && (fabsf(v) < 100.0f);
    unsigned long long m = __ballot(plaus);
    if (threadIdx.x==0) *flag = (m == ~0ULL) ? 1 : 0;
}

// ---------------- convert float inputs to fp32 workspace (flattened grid) ----------------
__global__ void k_cvt(Ptrs ptrs, float* __restrict__ dst, const int* __restrict__ flag){
    long i4 = (long)blockIdx.x*256 + threadIdx.x;
    const long TOT4 = CVT_OFF.v[31]/4;
    if (i4 >= TOT4) return;
    long e = i4*4;
    int t = 0;
    #pragma unroll
    for(int i=1;i<31;i++) t += (e >= CVT_OFF.v[i]) ? 1 : 0;
    long l4 = i4 - CVT_OFF.v[t]/4;
    const void* src = ptrs.p[t];
    float4 o;
    if (*flag){
        ushort4 u = ((const ushort4*)src)[l4];
        o.x=b2f(u.x); o.y=b2f(u.y); o.z=b2f(u.z); o.w=b2f(u.w);
    } else {
        o = ((const float4*)src)[l4];
    }
    *(float4*)(dst + CVT_OFF.v[t] + l4*4) = o;
}

// ======== WT precompute: 24 H×H matrices -> bf16, FRAGMENT-MAJOR per 32-k chunk ========
// [0..11]=Wa_main(d,k), [12..14]=Wu2[:H], [15..17]=Wu1[:H], [18..20]=Wu1[H:2H], [21..23]=Wzm1
// Layout per (mi, k0/32) chunk (8192 u16 = 16KB):
//   idx = nt*512 + quad*128 + l15*8 + j  <-  src[k0 + quad*8 + j][nt*16 + l15]
__global__ void k_wt(const float* __restrict__ Wam, const float* __restrict__ Wu2,
                     const float* __restrict__ Wu1, const float* __restrict__ Wzm1,
                     u16* __restrict__ WT){
    int mi = blockIdx.z;
    const float* src;
    if (mi<12)      src = Wam  + (size_t)mi*H_*H_;
    else if (mi<15) src = Wu2  + (size_t)(mi-12)*(H_+6)*H_;
    else if (mi<18) src = Wu1  + (size_t)(mi-15)*2*H_*H_;
    else if (mi<21) src = Wu1  + (size_t)(mi-18)*2*H_*H_ + (size_t)H_*H_;
    else            src = Wzm1 + (size_t)(mi-21)*H_*H_;
    __shared__ float t[32][33];
    int x = threadIdx.x, y = threadIdx.y;
    int k0 = blockIdx.y*32, n0 = blockIdx.x*32;
    for(int yy=y; yy<32; yy+=8) t[yy][x] = src[(size_t)(k0+yy)*H_ + n0+x];
    __syncthreads();
    u16* dst = WT + ((size_t)mi*8 + (k0>>5))*8192;
    int quad = x>>3, j = x&7;           // kk = x = quad*8+j
    for(int yy=y; yy<32; yy+=8){
        int n = n0+yy, nt = n>>4, lv = n&15;
        dst[nt*512 + quad*128 + lv*8 + j] = f2b(t[x][yy]);
    }
}

// ---------------- vertex embedding: 8 rows per block ----------------
__global__ void k_embed(const u16* __restrict__ atom, const float* __restrict__ Wv,
                        const float* __restrict__ bv, float* __restrict__ vf,
                        u16* __restrict__ vf_bf, const int* __restrict__ flag){
    __shared__ float arow[8][A_];
    int r0 = blockIdx.x*8; int j = threadIdx.x;
    int fl = *flag;
    for(int i=j;i<8*A_;i+=256){
        int r=i/A_, a=i-r*A_;
        arow[r][a] = fl ? b2f(atom[(size_t)(r0+r)*A_+a])
                        : ((const float*)atom)[(size_t)(r0+r)*A_+a];
    }
    __syncthreads();
    float acc[8];
    float bj = bv[j];
    #pragma unroll
    for(int r=0;r<8;r++) acc[r]=bj;
    for(int a=0;a<A_;a++){
        float w = Wv[a*H_+j];
        #pragma unroll
        for(int r=0;r<8;r++) acc[r] += arow[r][a]*w;
    }
    #pragma unroll
    for(int r=0;r<8;r++){
        float v = acc[r];
        v = v>0.f ? v : 0.01f*v;
        vf[(size_t)(r0+r)*H_+j] = v;
        vf_bf[(size_t)(r0+r)*H_+j] = f2b(v);
    }
}

// ---------------- sf0 ----------------
__global__ void k_sf0(const float* __restrict__ vf, const float* __restrict__ dmask,
                      float* __restrict__ sf){
    int b = blockIdx.x, h = threadIdx.x;
    __shared__ float mk[N_];
    for(int n=threadIdx.x;n<N_;n+=256) mk[n] = dmask[b*N_+n];
    __syncthreads();
    float s=0.f;
    #pragma unroll 8
    for(int n=0;n<N_;n++) s += mk[n]*vf[((size_t)b*N_+n)*H_ + h];
    sf[b*H_+h]=s;
}

// ======== S1: batched GEMV from sf: asw(0..3), s2m(4), ssf(5), st(6 = s2m@Wzm2) ========
__global__ void k_s1(int d, const float* __restrict__ sf,
    const float* __restrict__ Was, const float* __restrict__ bas,
    const float* __restrict__ Wbmm,
    const float* __restrict__ Ws2m, const float* __restrict__ bs2m,
    const float* __restrict__ Wsup, const float* __restrict__ bsup,
    const float* __restrict__ Wzm2, const float* __restrict__ bzm2,
    float* __restrict__ asw, float* __restrict__ s2m, float* __restrict__ ssf,
    float* __restrict__ st)
{
    int b = blockIdx.x, m = blockIdx.y, j = threadIdx.x;
    __shared__ float sfl[H_];
    __shared__ float s2l[H_];
    sfl[j] = sf[b*H_+j];
    __syncthreads();
    if (m == 6){
        // stage 1: s2m_local (identical expression/order to seg m==4)
        const float* W = Ws2m + (size_t)d*H_*H_;
        float acc = bs2m[d*H_+j];
        #pragma unroll 8
        for(int h=0;h<H_;h++) acc += sfl[h]*W[h*H_+j];
        s2l[j] = tanhf(acc);
        __syncthreads();
        // stage 2: st = bzm2 + s2m @ Wzm2  (order == old partial scheme: bzm2 then h ascending)
        const float* W2 = Wzm2 + (size_t)d*H_*H_;
        float acc2 = bzm2[d*H_+j];
        #pragma unroll 8
        for(int h=0;h<H_;h++) acc2 += s2l[h]*W2[h*H_+j];
        st[b*H_+j] = acc2;
        return;
    }
    const float* W; float bias;
    if (m < 4){ W = Was + (size_t)(d*K_+m)*H_*H_; bias = bas[(d*K_+m)*H_+j]; }
    else if (m==4){ W = Ws2m + (size_t)d*H_*H_; bias = bs2m[d*H_+j]; }
    else { W = Wsup + (size_t)d*H_*H_; bias = bsup[d*H_+j]; }
    float acc = bias;
    #pragma unroll 8
    for(int h=0;h<H_;h++) acc += sfl[h]*W[h*H_+j];
    float v = tanhf(acc);
    if (m < 4) asw[(b*K_+m)*H_+j] = v * Wbmm[(d*K_+m)*H_+j];
    else if (m==4) s2m[b*H_+j] = v;
    else ssf[b*H_+j] = v;
}

// ======== async W staging: one 16KB chunk, linear, 4×16B DMA per thread ========
__device__ __forceinline__ void stageW(const u16* __restrict__ g, u16* l){
    int t = threadIdx.x;
    const u16* gs = g + t*8;
    u16* ls = l + t*8;
    #pragma unroll
    for(int it=0; it<4; ++it)
        __builtin_amdgcn_global_load_lds(
            (const __attribute__((address_space(1))) void*)(gs + it*2048),
            (__attribute__((address_space(3))) void*)(ls + it*2048),
            16, 0, 0);
}

// ================= 64-row MFMA core: A in regs (rolling 4-deep), W via global_load_lds dbuf =================
__device__ __forceinline__ void gemm_ldsW(const u16* __restrict__ Abf,
                                          const u16* __restrict__ WTg,
                                          u16* Wlds, f32x4 acc[2][8])
{
    int tid = threadIdx.x;
    int lane = tid & 63, wave = tid >> 6;
    int wy = wave >> 1, wx = wave & 1;
    int quad = lane >> 4, l15 = lane & 15;
    const u16* aP0 = Abf + (size_t)(wy*32 + l15)*H_ + quad*8;
    const u16* aP1 = aP0 + 16*H_;
    bf16x8 a[4][2];
    #pragma unroll
    for(int s=0;s<3;s++){
        a[s][0] = *(const bf16x8*)(aP0 + s*32);
        a[s][1] = *(const bf16x8*)(aP1 + s*32);
    }
    stageW(WTg, Wlds);
    #pragma unroll
    for(int mt=0;mt<2;mt++)
        #pragma unroll
        for(int nt=0;nt<8;nt++) acc[mt][nt]=(f32x4){0.f,0.f,0.f,0.f};
    __syncthreads();
    #pragma unroll
    for(int s=0;s<8;s++){
        if (s<7) stageW(WTg + (size_t)(s+1)*8192, Wlds + ((s+1)&1)*8192);
        if (s<5){
            int sl = s+3;
            a[sl&3][0] = *(const bf16x8*)(aP0 + sl*32);
            a[sl&3][1] = *(const bf16x8*)(aP1 + sl*32);
        }
        const u16* wb = Wlds + (s&1)*8192 + wx*4096 + quad*128 + l15*8;
        bf16x8 w[8];
        #pragma unroll
        for(int nt=0;nt<8;nt++) w[nt] = *(const bf16x8*)(wb + nt*512);
        #pragma unroll
        for(int mt=0;mt<2;mt++)
            #pragma unroll
            for(int nt=0;nt<8;nt++)
                acc[mt][nt] = __builtin_amdgcn_mfma_f32_16x16x32_bf16(
                    a[s&3][mt], w[nt], acc[mt][nt], 0,0,0);
        __syncthreads();
    }
}

// ================= 32-row MFMA core: A in regs (rolling 4-deep), W via global_load_lds dbuf =================
// 4 waves, wave tile 16x128: rows wy*16+l15, cols wx*128..+127. acc[8].
__device__ __forceinline__ void gemm_ldsW32(const u16* __restrict__ Abf,
                                            const u16* __restrict__ WTg,
                                            u16* Wlds, f32x4 acc[8])
{
    int tid = threadIdx.x;
    int lane = tid & 63, wave = tid >> 6;
    int wy = wave >> 1, wx = wave & 1;
    int quad = lane >> 4, l15 = lane & 15;
    const u16* aP0 = Abf + (size_t)(wy*16 + l15)*H_ + quad*8;
    bf16x8 a[4];
    #pragma unroll
    for(int s=0;s<3;s++) a[s] = *(const bf16x8*)(aP0 + s*32);
    stageW(WTg, Wlds);
    #pragma unroll
    for(int nt=0;nt<8;nt++) acc[nt]=(f32x4){0.f,0.f,0.f,0.f};
    __syncthreads();
    #pragma unroll
    for(int s=0;s<8;s++){
        if (s<7) stageW(WTg + (size_t)(s+1)*8192, Wlds + ((s+1)&1)*8192);
        if (s<5) a[(s+3)&3] = *(const bf16x8*)(aP0 + (s+3)*32);
        const u16* wb = Wlds + (s&1)*8192 + wx*4096 + quad*128 + l15*8;
        bf16x8 w[8];
        #pragma unroll
        for(int nt=0;nt<8;nt++) w[nt] = *(const bf16x8*)(wb + nt*512);
        #pragma unroll
        for(int nt=0;nt<8;nt++)
            acc[nt] = __builtin_amdgcn_mfma_f32_16x16x32_bf16(
                a[s&3], w[nt], acc[nt], 0,0,0);
        __syncthreads();
    }
}

// ================= 32-row MFMA core: A from (XOR-swizzled, stride-256) LDS tile =================
__device__ __forceinline__ void gemm_lds232(const u16* Als, const u16* __restrict__ WTg,
                                            u16* Wlds, f32x4 acc[8])
{
    int tid = threadIdx.x;
    int lane = tid & 63, wave = tid >> 6;
    int wy = wave >> 1, wx = wave & 1;
    int quad = lane >> 4, l15 = lane & 15;
    stageW(WTg, Wlds);
    #pragma unroll
    for(int nt=0;nt<8;nt++) acc[nt]=(f32x4){0.f,0.f,0.f,0.f};
    __syncthreads();    // covers tile writes + W chunk0 DMA
    int r0 = wy*16 + l15;
    #pragma unroll
    for(int s=0;s<8;s++){
        if (s<7) stageW(WTg + (size_t)(s+1)*8192, Wlds + ((s+1)&1)*8192);
        int c0 = s*32 + quad*8;
        bf16x8 a0 = *(const bf16x8*)(Als + r0*256 + (c0 ^ ((r0&7)<<3)));
        const u16* wb = Wlds + (s&1)*8192 + wx*4096 + quad*128 + l15*8;
        bf16x8 w[8];
        #pragma unroll
        for(int nt=0;nt<8;nt++) w[nt] = *(const bf16x8*)(wb + nt*512);
        #pragma unroll
        for(int nt=0;nt<8;nt++)
            acc[nt] = __builtin_amdgcn_mfma_f32_16x16x32_bf16(a0, w[nt], acc[nt], 0,0,0);
        __syncthreads();
    }
}

// ================= big GEMM over vf (bf16 A), 64-row tiles (proven best) =================
__global__ __launch_bounds__(256,3) void k_gemm_big(int d, const u16* __restrict__ vf_bf,
    const u16* __restrict__ WT, const float* __restrict__ ba_main,
    const float* __restrict__ bbmm, const float* __restrict__ bu1,
    const float* __restrict__ asw, float* __restrict__ score,
    float* __restrict__ proj_u2, float* __restrict__ pu1a)
{
    __shared__ __attribute__((aligned(16))) u16 Wlds[2*8192];
    int m0 = blockIdx.x*64;
    int seg = blockIdx.y;
    int b = m0 >> 9;
    int mi;
    if (seg < 4)      mi = d*4+seg;
    else if (seg==4)  mi = 12+d;
    else              mi = 15+d;
    f32x4 acc[2][8];
    gemm_ldsW(vf_bf + (size_t)m0*H_, WT + (size_t)mi*H_*H_, Wlds, acc);
    int tid=threadIdx.x, lane=tid&63, wave=tid>>6;
    int wy=wave>>1, wx=wave&1, quad=lane>>4, l15=lane&15;
    if (seg < 4){
        float* sred = (float*)Wlds;   // alias: loop done (post-barrier)
        const float* aswp = asw + (size_t)(b*K_+seg)*H_;
        const float* bap  = ba_main + (size_t)(d*K_+seg)*H_;
        float bbv[8], awv[8];
        #pragma unroll
        for(int nt=0;nt<8;nt++){
            int col = wx*128+nt*16+l15;
            bbv[nt]=bap[col]; awv[nt]=aswp[col];
        }
        #pragma unroll
        for(int mt=0;mt<2;mt++)
            #pragma unroll
            for(int r=0;r<4;r++){
                float p=0.f;
                #pragma unroll
                for(int nt=0;nt<8;nt++)
                    p += tanhf(acc[mt][nt][r]+bbv[nt])*awv[nt];
                int row = wy*32+mt*16+quad*4+r;
                sred[row*33 + wx*16+l15] = p;
            }
        __syncthreads();
        if (tid < 64){
            float s=0.f;
            #pragma unroll 8
            for(int i=0;i<32;i++) s += sred[tid*33+i];
            score[(size_t)(b*K_+seg)*N_ + (m0&511) + tid] = s + bbmm[d*K_+seg];
        }
    } else if (seg==4){
        #pragma unroll
        for(int mt=0;mt<2;mt++)
            #pragma unroll
            for(int nt=0;nt<8;nt++){
                int col = wx*128+nt*16+l15;
                #pragma unroll
                for(int r=0;r<4;r++){
                    int row = m0 + wy*32+mt*16+quad*4+r;
                    proj_u2[(size_t)row*H_+col] = acc[mt][nt][r];
                }
            }
    } else {
        const float* bp = bu1 + d*H_;
        #pragma unroll
        for(int mt=0;mt<2;mt++)
            #pragma unroll
            for(int nt=0;nt<8;nt++){
                int col = wx*128+nt*16+l15;
                float bb = bp[col];
                #pragma unroll
                for(int r=0;r<4;r++){
                    int row = m0 + wy*32+mt*16+quad*4+r;
                    pu1a[(size_t)row*H_+col] = acc[mt][nt][r] + bb;
                }
            }
    }
}

// ===== FUSED: main_self GEMM + z_main GEMM + GRU vf update — 32-row blocks for occupancy =====
// Grid 512 blocks (vs 256): 2-3 blocks/CU instead of 1 -> latency hiding across the
// two serial GEMMs. Per-element MFMA sequence & epilogue expressions unchanged (bit-identical).
__global__ __launch_bounds__(256,3) void k_msup(int d, const u16* __restrict__ neims,
    const u16* __restrict__ WT, const float* __restrict__ pu1a,
    const float* __restrict__ bzm1, const float* __restrict__ st,
    const float* __restrict__ s2m, float* __restrict__ vf, u16* __restrict__ vf_bf)
{
    __shared__ __attribute__((aligned(16))) u16 Wlds[2*8192];   // 32KB
    __shared__ __attribute__((aligned(16))) u16 ms_lds[32*256]; // 16KB
    int m0 = blockIdx.x*32; int b = m0>>9;
    f32x4 acc[8];
    gemm_ldsW32(neims + (size_t)m0*H_, WT + (size_t)(18+d)*H_*H_, Wlds, acc);
    int tid=threadIdx.x, lane=tid&63, wave=tid>>6;
    int wy=wave>>1, wx=wave&1, quad=lane>>4, l15=lane&15;
    // epilogue 1: main_self
    #pragma unroll
    for(int nt=0;nt<8;nt++){
        int col = wx*128+nt*16+l15;
        #pragma unroll
        for(int r=0;r<4;r++){
            int rl = wy*16+quad*4+r;
            float v = acc[nt][r] + pu1a[(size_t)(m0+rl)*H_+col];
            v = v>0.f? v : 0.1f*v;
            acc[nt][r] = v;
            ms_lds[rl*256 + (col ^ ((rl&7)<<3))] = f2b(v);
        }
    }
    // GEMM2 over ms (A from LDS); leading barrier inside covers ms_lds writes
    f32x4 acc2[8];
    gemm_lds232(ms_lds, WT + (size_t)(21+d)*H_*H_, Wlds, acc2);
    #pragma unroll
    for(int nt=0;nt<8;nt++){
        int col = wx*128+nt*16+l15;
        float bz = bzm1[d*H_+col];
        float stv = st[b*H_+col];
        float sm = s2m[b*H_+col];
        #pragma unroll
        for(int r=0;r<4;r++){
            int row = m0 + wy*16+quad*4+r;
            float z = sigmoidf_(acc2[nt][r] + bz + stv);
            float msv = acc[nt][r];
            float o = (1.f-z)*msv + z*sm;
            vf[(size_t)row*H_+col] = o;
            vf_bf[(size_t)row*H_+col] = f2b(o);
        }
    }
}

// ===== FUSED: masked softmax + t (attn@vf) + m1 (t@Wm) per (b,k) =====
__global__ __launch_bounds__(512) void k_att(int d, const float* __restrict__ score,
    const float* __restrict__ dmask, const float* __restrict__ vf,
    const float* __restrict__ Wm, const float* __restrict__ bm,
    float* __restrict__ m2s)
{
    int b = blockIdx.x, k = blockIdx.y, tid = threadIdx.x;
    __shared__ float at[N_];
    __shared__ float sh[256];
    __shared__ float tp[2][256];
    const float* a = score + (size_t)(b*K_+k)*N_;
    float v0=0.f, v1=0.f, e0=0.f, e1=0.f;
    if (tid < 256){ v0=a[tid]; v1=a[tid+256]; sh[tid]=fmaxf(v0,v1); }
    __syncthreads();
    for(int s=128;s>0;s>>=1){ if(tid<s) sh[tid]=fmaxf(sh[tid],sh[tid+s]); __syncthreads(); }
    float m = sh[0]; __syncthreads();
    if (tid < 256){
        e0 = expf(v0-m)*dmask[b*N_+tid];
        e1 = expf(v1-m)*dmask[b*N_+tid+256];
        sh[tid]=e0+e1;
    }
    __syncthreads();
    for(int s=128;s>0;s>>=1){ if(tid<s) sh[tid]+=sh[tid+s]; __syncthreads(); }
    float S = sh[0];
    float inv = 1.f/(S+1e-6f);
    float sumattn = S*inv;
    if (tid < 256){ at[tid]=e0*inv; at[tid+256]=e1*inv; }
    __syncthreads();
    // t partials: half 0 covers n in [0,256), half 1 covers [256,512)
    int h = tid & 255, half = tid >> 8;
    {
        float acc=0.f;
        const float* vfp = vf + ((size_t)b*N_ + half*256)*H_ + h;
        const float* atp = at + half*256;
        #pragma unroll 8
        for(int n=0;n<256;n++) acc += atp[n]*vfp[(size_t)n*H_];
        tp[half][h]=acc;
    }
    __syncthreads();
    // m1: m2s[j] = sumattn*bm[j] + sum_h (tp0[h]+tp1[h]) * Wm[h][j]  (h split across halves)
    {
        const float* W = Wm + (size_t)(d*K_+k)*H_*H_;
        float acc = (half==0) ? sumattn*bm[(d*K_+k)*H_+h] : 0.f;
        int h0 = half*128;
        #pragma unroll 8
        for(int t2=h0; t2<h0+128; t2++) acc += (tp[0][t2]+tp[1][t2])*W[(size_t)t2*H_+h];
        at[half*256+h]=acc;   // at[] free now; reuse for partial exchange
    }
    __syncthreads();
    if (tid < 256) m2s[(size_t)(b*K_+k)*H_+tid] = at[tid]+at[256+tid];
}

// ======== M2: mts partials ========
__global__ void k_m2(int d, const float* __restrict__ m2s, const float* __restrict__ Wm2s,
                     float* __restrict__ mtsp)
{
    int b=blockIdx.x, c=blockIdx.y, j=threadIdx.x;
    __shared__ float xl[H_];
    xl[j]=m2s[(size_t)(b*K_+c)*H_+j];
    __syncthreads();
    const float* W = Wm2s + (size_t)d*(K_*H_)*H_ + (size_t)(c*H_)*H_;
    float acc=0.f;
    #pragma unroll 8
    for(int h=0;h<H_;h++) acc += xl[h]*W[h*H_+j];
    mtsp[((size_t)c*B_+b)*H_+j]=acc;
}

// ===== FUSED: mts + m3 (p1,p2) + sf GRU update, one block per b =====
__global__ __launch_bounds__(512) void k_fin(int d, const float* __restrict__ mtsp,
    const float* __restrict__ bm2s, const float* __restrict__ ssf,
    const float* __restrict__ Wzs1, const float* __restrict__ Wzs2,
    const float* __restrict__ bzs1, const float* __restrict__ bzs2,
    float* __restrict__ sf)
{
    int b = blockIdx.x, tid = threadIdx.x;
    int j = tid & 255, g = tid >> 8;
    __shared__ float mtsl[256], ssl[256], pp[2][256];
    if (g==0){
        float acc = bm2s[d*H_+j];
        #pragma unroll
        for(int c=0;c<4;c++) acc += mtsp[((size_t)c*B_+b)*H_+j];
        mtsl[j] = tanhf(acc);
    } else {
        ssl[j] = ssf[b*H_+j];
    }
    __syncthreads();
    {
        const float* W = (g ? Wzs2 : Wzs1) + (size_t)d*H_*H_;
        const float* x = g ? mtsl : ssl;
        float acc = 0.f;
        #pragma unroll 8
        for(int h=0;h<H_;h++) acc += x[h]*W[h*H_+j];
        pp[g][j] = acc;
    }
    __syncthreads();
    if (g==0){
        float z = sigmoidf_(pp[0][j]+bzs1[d*H_+j]+pp[1][j]+bzs2[d*H_+j]);
        sf[b*H_+j] = (1.f-z)*ssl[j] + z*mtsl[j];
    }
}

// ---- nei: 4 rows per block, writes bf16 directly ----
__global__ void k_nei(int d, const int* __restrict__ anb, const int* __restrict__ bnb,
    const float* __restrict__ nbm, const float* __restrict__ bond,
    const float* __restrict__ Wu2, const float* __restrict__ bu2,
    const float* __restrict__ proj_u2, u16* __restrict__ nei_bf)
{
    __shared__ float W2s[6][256];
    __shared__ float bfeat[4][NB_][6];
    __shared__ int ai[4][NB_]; __shared__ int bi[4][NB_]; __shared__ float mk[4][NB_];
    int r0 = blockIdx.x*4; int b = r0 >> 9; int h = threadIdx.x;
    const float* W2 = Wu2 + (size_t)d*(H_+6)*H_ + (size_t)H_*H_;
    for(int i=h;i<6*H_;i+=256) W2s[i>>8][i&255] = W2[i];
    if (h < 4*NB_){
        int r=h/NB_, jn=h-r*NB_;
        ai[r][jn]=anb[(size_t)(r0+r)*NB_+jn];
        bi[r][jn]=bnb[(size_t)(r0+r)*NB_+jn];
        mk[r][jn]=nbm[(size_t)(r0+r)*NB_+jn];
    }
    __syncthreads();
    if (h < 4*NB_*6){
        int r=h/(NB_*6), rem=h-r*(NB_*6), jn=rem/6, i=rem-jn*6;
        bfeat[r][jn][i]=bond[((size_t)b*E_+bi[r][jn])*6+i];
    }
    __syncthreads();
    float bu = bu2[d*H_+h];
    #pragma unroll
    for(int r=0;r<4;r++){
        float acc=0.f;
        #pragma unroll
        for(int jn=0;jn<NB_;jn++){
            float v = proj_u2[((size_t)b*N_+ai[r][jn])*H_+h] + bu;
            #pragma unroll
            for(int i=0;i<6;i++) v += bfeat[r][jn][i]*W2s[i][h];
            v = v>0.f? v : 0.1f*v;
            acc += mk[r][jn]*v;
        }
        nei_bf[(size_t)(r0+r)*H_+h]=f2b(acc);
    }
}

// ---------------- final output ----------------
__global__ void k_out(const float* __restrict__ vf, const float* __restrict__ sf,
                      void* __restrict__ out, const int* __restrict__ flag){
    int idx = blockIdx.x*256 + threadIdx.x;
    const int total = M_*H_ + B_*H_;
    if (idx >= total) return;
    float v = (idx < M_*H_) ? vf[idx] : sf[idx - M_*H_];
    if (*flag) ((unsigned short*)out)[idx] = f2b(v);
    else       ((float*)out)[idx] = v;
}

extern "C" void kernel_launch(void* const* d_in, const int* in_sizes, int n_in,
                              void* d_out, int out_size, void* d_ws, size_t ws_size,
                              hipStream_t stream)
{
    const int* anb = (const int*)d_in[2];
    const int* bnb = (const int*)d_in[3];

    float* ws   = (float*)d_ws;
    int*   flag = (int*)ws;                 // 256 B reserved
    float* cvt  = ws + 64;
    float* p    = cvt + ((CVT_OFF.v[31] + 63) & ~63L);
    float* vf        = p; p += (size_t)M_*H_;
    float* proj_u2   = p; p += (size_t)M_*H_;
    float* pu1a      = p; p += (size_t)M_*H_;
    u16*   vf_bf     = (u16*)p; p += (size_t)M_*H_/2;
    u16*   neims     = (u16*)p; p += (size_t)M_*H_/2;
    float* sf        = p; p += B_*H_;
    float* score     = p; p += B_*K_*N_;
    float* asw       = p; p += B_*K_*H_;
    float* s2m       = p; p += B_*H_;
    float* ssf       = p; p += B_*H_;
    float* st        = p; p += B_*H_;
    float* m2s       = p; p += B_*K_*H_;
    float* mtsp      = p; p += 4*B_*H_;
    u16*   WT        = (u16*)p;             // 24 * H*H bf16 = 3.1 MB

    const float* cBond = cvt + CVT_OFF.v[0];
    const float* cNbm  = cvt + CVT_OFF.v[1];
    const float* cDm   = cvt + CVT_OFF.v[2];
    const float* cWv   = cvt + CVT_OFF.v[3];
    const float* cbv   = cvt + CVT_OFF.v[4];
    const float* cWam  = cvt + CVT_OFF.v[5];
    const float* cbam  = cvt + CVT_OFF.v[6];
    const float* cWas  = cvt + CVT_OFF.v[7];
    const float* cbas  = cvt + CVT_OFF.v[8];
    const float* cWm   = cvt + CVT_OFF.v[9];
    const float* cbm   = cvt + CVT_OFF.v[10];
    const float* cWbmm = cvt + CVT_OFF.v[11];
    const float* cbbmm = cvt + CVT_OFF.v[12];
    const float* cWm2s = cvt + CVT_OFF.v[13];
    const float* cbm2s = cvt + CVT_OFF.v[14];
    const float* cWs2m = cvt + CVT_OFF.v[15];
    const float* cbs2m = cvt + CVT_OFF.v[16];
    const float* cWsup = cvt + CVT_OFF.v[17];
    const float* cbsup = cvt + CVT_OFF.v[18];
    const float* cWzm1 = cvt + CVT_OFF.v[19];
    const float* cbzm1 = cvt + CVT_OFF.v[20];
    const float* cWzm2 = cvt + CVT_OFF.v[21];
    const float* cbzm2 = cvt + CVT_OFF.v[22];
    const float* cWzs1 = cvt + CVT_OFF.v[23];
    const float* cbzs1 = cvt + CVT_OFF.v[24];
    const float* cWzs2 = cvt + CVT_OFF.v[25];
    const float* cbzs2 = cvt + CVT_OFF.v[26];
    const float* cWu2  = cvt + CVT_OFF.v[27];
    const float* cbu2  = cvt + CVT_OFF.v[28];
    const float* cWu1  = cvt + CVT_OFF.v[29];
    const float* cbu1  = cvt + CVT_OFF.v[30];

    Ptrs ptrs;
    {
        int idx[31] = {1,4,5,6,7,8,9,10,11,12,13,14,15,16,17,18,19,20,21,
                       22,23,24,25,26,27,28,29,30,31,32,33};
        for(int i=0;i<31;i++) ptrs.p[i] = d_in[idx[i]];
    }

    k_detect<<<1,64,0,stream>>>((const unsigned short*)d_in[6], flag);
    {
        long tot4 = CVT_OFF.v[31]/4;
        int gx = (int)((tot4 + 255)/256);
        k_cvt<<<gx,256,0,stream>>>(ptrs, cvt, flag);
    }
    k_wt<<<dim3(8,8,24),dim3(32,8),0,stream>>>(cWam, cWu2, cWu1, cWzm1, WT);

    k_embed<<<M_/8,256,0,stream>>>((const u16*)d_in[0], cWv, cbv, vf, vf_bf, flag);
    k_sf0<<<B_,256,0,stream>>>(vf, cDm, sf);
    for(int d=0; d<D_; d++){
        k_s1<<<dim3(B_,7),256,0,stream>>>(d, sf, cWas, cbas, cWbmm,
                                          cWs2m, cbs2m, cWsup, cbsup,
                                          cWzm2, cbzm2, asw, s2m, ssf, st);
        k_gemm_big<<<dim3(M_/64,6),256,0,stream>>>(d, vf_bf, WT, cbam, cbbmm, cbu1,
                                                   asw, score, proj_u2, pu1a);
        k_att<<<dim3(B_,K_),512,0,stream>>>(d, score, cDm, vf, cWm, cbm, m2s);
        k_nei<<<M_/4,256,0,stream>>>(d, anb, bnb, cNbm, cBond, cWu2, cbu2, proj_u2, neims);
        k_msup<<<M_/32,256,0,stream>>>(d, neims, WT, pu1a, cbzm1, st, s2m, vf, vf_bf);
        k_m2<<<dim3(B_,4),256,0,stream>>>(d, m2s, cWm2s, mtsp);
        k_fin<<<B_,512,0,stream>>>(d, mtsp, cbm2s, ssf, cWzs1, cWzs2, cbzs1, cbzs2, sf);
    }
    k_out<<<(M_*H_+B_*H_+255)/256,256,0,stream>>>(vf, sf, d_out, flag);
}